// Round 2
// baseline (2586.263 us; speedup 1.0000x reference)
//
#include <hip/hip_runtime.h>
#include <hip/hip_bf16.h>

#define H 8
#define C 16
#define HC 128
#define NEG_SLOPE 0.2f

// ---------------- atomic float max (int-ordered trick) ----------------
__device__ inline void atomicMaxFloat(float* addr, float val) {
    if (val >= 0.f) {
        atomicMax((int*)addr, __float_as_int(val));
    } else {
        atomicMin((unsigned int*)addr, (unsigned int)__float_as_int(val));
    }
}

// ---------------- init per-layer buffers ----------------
__global__ void init_kernel(float* __restrict__ m, float* __restrict__ z,
                            float* __restrict__ out, int n) {
    int i = blockIdx.x * 256 + threadIdx.x;
    if (i < n * H) { m[i] = -INFINITY; z[i] = 0.f; }
    if (i < n * HC) out[i] = 0.f;
}

// ---------------- zero small pool buffers ----------------
__global__ void zero_kernel(float* __restrict__ p, int n) {
    int i = blockIdx.x * 256 + threadIdx.x;
    if (i < n) p[i] = 0.f;
}

// ---------------- GEMM: h[n,128] = x[n,K] @ W[K,128] ----------------
template <int K>
__global__ void gemm_kernel(const float* __restrict__ x, const float* __restrict__ W,
                            float* __restrict__ h, int n) {
    const int ROWS = 16;
    __shared__ float xs[ROWS][K];
    int col  = threadIdx.x & 127;
    int half = threadIdx.x >> 7;  // 0..1
    int row0 = blockIdx.x * ROWS;

    for (int idx = threadIdx.x; idx < ROWS * K; idx += 256) {
        int rr = idx / K, kk = idx - rr * K;
        int gr = row0 + rr;
        xs[rr][kk] = (gr < n) ? x[(size_t)gr * K + kk] : 0.f;
    }
    __syncthreads();

    float acc[ROWS / 2];
#pragma unroll
    for (int i = 0; i < ROWS / 2; ++i) acc[i] = 0.f;

    for (int k = 0; k < K; ++k) {
        float wv = W[k * HC + col];
#pragma unroll
        for (int i = 0; i < ROWS / 2; ++i)
            acc[i] = fmaf(xs[2 * i + half][k], wv, acc[i]);
    }
#pragma unroll
    for (int i = 0; i < ROWS / 2; ++i) {
        int row = row0 + 2 * i + half;
        if (row < n) h[(size_t)row * HC + col] = acc[i];
    }
}

// ---------------- attention coefficients a_src/a_dst [N,H] ----------------
__global__ void att_kernel(const float* __restrict__ h, const float* __restrict__ as_,
                           const float* __restrict__ ad_, float* __restrict__ asrc,
                           float* __restrict__ adst, int n) {
    int i = blockIdx.x * 256 + threadIdx.x;  // i = node*H + head
    if (i >= n * H) return;
    int hd = i & (H - 1);
    const float4* hv = (const float4*)(h + (size_t)i * C);
    const float4* sv = (const float4*)(as_ + hd * C);
    const float4* dv = (const float4*)(ad_ + hd * C);
    float s = 0.f, d = 0.f;
#pragma unroll
    for (int j = 0; j < 4; ++j) {
        float4 a = hv[j], u = sv[j], v = dv[j];
        s += a.x * u.x + a.y * u.y + a.z * u.z + a.w * u.w;
        d += a.x * v.x + a.y * v.y + a.z * v.z + a.w * v.w;
    }
    asrc[i] = s;
    adst[i] = d;
}

// ---------------- edge pass 1: leaky score + segment max ----------------
__global__ void edge_score_kernel(const int* __restrict__ ei,
                                  const float* __restrict__ asrc,
                                  const float* __restrict__ adst,
                                  float* __restrict__ p, float* __restrict__ m,
                                  int E, int N) {
    int i = blockIdx.x * 256 + threadIdx.x;
    if (i >= E + N) return;
    int s, d;
    if (i < E) { s = ei[i]; d = ei[E + i]; }
    else       { s = d = i - E; }
    const float* a = asrc + (size_t)s * H;
    const float* b = adst + (size_t)d * H;
#pragma unroll
    for (int hd = 0; hd < H; ++hd) {
        float e = a[hd] + b[hd];
        e = e > 0.f ? e : NEG_SLOPE * e;
        p[(size_t)i * H + hd] = e;
        atomicMaxFloat(&m[(size_t)d * H + hd], e);
    }
}

// ---------------- edge pass 2: exp + segment sum ----------------
__global__ void edge_exp_kernel(const int* __restrict__ ei, float* __restrict__ p,
                                const float* __restrict__ m, float* __restrict__ z,
                                int E, int N) {
    int i = blockIdx.x * 256 + threadIdx.x;
    if (i >= E + N) return;
    int d = (i < E) ? ei[E + i] : i - E;
#pragma unroll
    for (int hd = 0; hd < H; ++hd) {
        float e  = p[(size_t)i * H + hd];
        float ex = __expf(e - m[(size_t)d * H + hd]);
        p[(size_t)i * H + hd] = ex;
        atomicAdd(&z[(size_t)d * H + hd], ex);
    }
}

// ---------------- edge pass 3: weighted aggregation ----------------
__global__ void edge_agg_kernel(const int* __restrict__ ei,
                                const float* __restrict__ p, const float* __restrict__ z,
                                const float* __restrict__ h, float* __restrict__ out,
                                int E, int N) {
    long long t = (long long)blockIdx.x * 256 + threadIdx.x;
    int edge = (int)(t >> 7);
    int col  = (int)(t & 127);
    if (edge >= E + N) return;
    int s, d;
    if (edge < E) { s = ei[edge]; d = ei[E + edge]; }
    else          { s = d = edge - E; }
    int hd = col >> 4;
    float alpha = p[(size_t)edge * H + hd] / (z[(size_t)d * H + hd] + 1e-16f);
    atomicAdd(&out[(size_t)d * HC + col], h[(size_t)s * HC + col] * alpha);
}

// ---------------- bias + relu ----------------
__global__ void bias_relu_kernel(float* __restrict__ out, const float* __restrict__ b, int n) {
    int i = blockIdx.x * 256 + threadIdx.x;
    if (i >= n * HC) return;
    float v = out[i] + b[i & 127];
    out[i] = v > 0.f ? v : 0.f;
}

// ---------------- global mean pool (sums + counts) ----------------
__global__ void pool_kernel(const float* __restrict__ x, const int* __restrict__ batch,
                            float* __restrict__ pooled, float* __restrict__ cnt, int n) {
    int t = blockIdx.x * 256 + threadIdx.x;
    if (t >= n * HC) return;
    int node = t >> 7, col = t & 127;
    int g = batch[node];
    atomicAdd(&pooled[(size_t)g * HC + col], x[t]);
    if (col == 0) atomicAdd(&cnt[g], 1.f);
}

// ---------------- final MLP: [G,128] -> relu(128->10) -> 10->1 ----------------
__global__ void mlp_kernel(const float* __restrict__ pooled, const float* __restrict__ cnt,
                           const float* __restrict__ fc1w, const float* __restrict__ fc1b,
                           const float* __restrict__ fc2w, const float* __restrict__ fc2b,
                           float* __restrict__ out, int G) {
    int g = blockIdx.x * 64 + threadIdx.x;
    if (g >= G) return;
    float inv = 1.f / fmaxf(cnt[g], 1.f);
    float hdn[10];
#pragma unroll
    for (int j = 0; j < 10; ++j) hdn[j] = fc1b[j];
    for (int k = 0; k < HC; ++k) {
        float v = pooled[(size_t)g * HC + k] * inv;
#pragma unroll
        for (int j = 0; j < 10; ++j) hdn[j] = fmaf(v, fc1w[k * 10 + j], hdn[j]);
    }
    float acc = fc2b[0];
#pragma unroll
    for (int j = 0; j < 10; ++j) acc = fmaf(fmaxf(hdn[j], 0.f), fc2w[j], acc);
    out[g] = acc;
}

extern "C" void kernel_launch(void* const* d_in, const int* in_sizes, int n_in,
                              void* d_out, int out_size, void* d_ws, size_t ws_size,
                              hipStream_t stream) {
    const int N = in_sizes[0] / 64;   // 50000
    const int E = in_sizes[1] / 2;    // 600000
    const int G = out_size;           // 500
    const int ET = E + N;             // edges incl. self loops

    const float* x     = (const float*)d_in[0];
    const int*   ei    = (const int*)d_in[1];    // int32 (harness converts int64 -> int32)
    const int*   batch = (const int*)d_in[2];
    const float* W1 = (const float*)d_in[3];
    const float* as1 = (const float*)d_in[4];
    const float* ad1 = (const float*)d_in[5];
    const float* b1 = (const float*)d_in[6];
    const float* W2 = (const float*)d_in[7];
    const float* as2 = (const float*)d_in[8];
    const float* ad2 = (const float*)d_in[9];
    const float* b2 = (const float*)d_in[10];
    const float* W3 = (const float*)d_in[11];
    const float* as3 = (const float*)d_in[12];
    const float* ad3 = (const float*)d_in[13];
    const float* b3 = (const float*)d_in[14];
    const float* fc1w = (const float*)d_in[15];
    const float* fc1b = (const float*)d_in[16];
    const float* fc2w = (const float*)d_in[17];
    const float* fc2b = (const float*)d_in[18];

    float* ws = (float*)d_ws;
    float* h      = ws;                          // N*128
    float* xb0    = h + (size_t)N * HC;          // N*128
    float* xb1    = xb0 + (size_t)N * HC;        // N*128
    float* m      = xb1 + (size_t)N * HC;        // N*8
    float* z      = m + (size_t)N * H;           // N*8
    float* asrc   = z + (size_t)N * H;           // N*8
    float* adst   = asrc + (size_t)N * H;        // N*8
    float* p      = adst + (size_t)N * H;        // ET*8
    float* pooled = p + (size_t)ET * H;          // G*128
    float* cnt    = pooled + (size_t)G * HC;     // G

    dim3 blk(256);
    int grid_nh  = (N * H + 255) / 256;
    int grid_nhc = (N * HC + 255) / 256;
    int grid_e   = (ET + 255) / 256;
    int grid_agg = (int)(((long long)ET * HC + 255) / 256);

    auto run_layer = [&](const float* xin, int K, const float* W, const float* as_,
                         const float* ad_, const float* b, float* out) {
        init_kernel<<<grid_nhc, blk, 0, stream>>>(m, z, out, N);
        if (K == 64)
            gemm_kernel<64><<<(N + 15) / 16, blk, 0, stream>>>(xin, W, h, N);
        else
            gemm_kernel<128><<<(N + 15) / 16, blk, 0, stream>>>(xin, W, h, N);
        att_kernel<<<grid_nh, blk, 0, stream>>>(h, as_, ad_, asrc, adst, N);
        edge_score_kernel<<<grid_e, blk, 0, stream>>>(ei, asrc, adst, p, m, E, N);
        edge_exp_kernel<<<grid_e, blk, 0, stream>>>(ei, p, m, z, E, N);
        edge_agg_kernel<<<grid_agg, blk, 0, stream>>>(ei, p, z, h, out, E, N);
        bias_relu_kernel<<<grid_nhc, blk, 0, stream>>>(out, b, N);
    };

    run_layer(x,   64,  W1, as1, ad1, b1, xb0);
    run_layer(xb0, 128, W2, as2, ad2, b2, xb1);
    run_layer(xb1, 128, W3, as3, ad3, b3, xb0);

    zero_kernel<<<(G * HC + G + 255) / 256, blk, 0, stream>>>(pooled, G * HC + G);
    pool_kernel<<<grid_nhc, blk, 0, stream>>>(xb0, batch, pooled, cnt, N);
    mlp_kernel<<<(G + 63) / 64, dim3(64), 0, stream>>>(pooled, cnt, fc1w, fc1b, fc2w, fc2b,
                                                       (float*)d_out, G);
}

// Round 3
// 688.863 us; speedup vs baseline: 3.7544x; 3.7544x over previous
//
#include <hip/hip_runtime.h>
#include <hip/hip_bf16.h>

#define H 8
#define C 16
#define HC 128
#define NEG_SLOPE 0.2f

// ---------------- zero int region ----------------
__global__ void zero_int_kernel(int* __restrict__ p, int n) {
    int i = blockIdx.x * 256 + threadIdx.x;
    if (i < n) p[i] = 0;
}

// ---------------- degree histogram over dst (incl. self loops) ----------------
__global__ void hist_kernel(const int* __restrict__ ei, int* __restrict__ deg, int E, int N) {
    int i = blockIdx.x * 256 + threadIdx.x;
    if (i >= E + N) return;
    int d = (i < E) ? ei[E + i] : i - E;
    atomicAdd(&deg[d], 1);
}

// ---------------- batch histogram ----------------
__global__ void batch_hist_kernel(const int* __restrict__ batch, int* __restrict__ gcnt, int N) {
    int i = blockIdx.x * 256 + threadIdx.x;
    if (i >= N) return;
    atomicAdd(&gcnt[batch[i]], 1);
}

// ---------------- single-block exclusive scan: rowptr[0..n] ----------------
__global__ void scan_kernel(const int* __restrict__ cnts, int* __restrict__ rowptr, int n) {
    __shared__ int sh[1024];
    __shared__ int carry;
    if (threadIdx.x == 0) carry = 0;
    __syncthreads();
    for (int base = 0; base < n; base += 1024) {
        int i = base + threadIdx.x;
        int v = (i < n) ? cnts[i] : 0;
        sh[threadIdx.x] = v;
        __syncthreads();
        for (int off = 1; off < 1024; off <<= 1) {
            int t = (threadIdx.x >= (unsigned)off) ? sh[threadIdx.x - off] : 0;
            __syncthreads();
            sh[threadIdx.x] += t;
            __syncthreads();
        }
        int incl = sh[threadIdx.x];
        if (i < n) rowptr[i] = carry + incl - v;  // exclusive
        int total = sh[1023];
        __syncthreads();
        if (threadIdx.x == 0) carry += total;
        __syncthreads();
    }
    if (threadIdx.x == 0) rowptr[n] = carry;
}

// ---------------- scatter edges into CSR (by destination) ----------------
__global__ void scatter_kernel(const int* __restrict__ ei, const int* __restrict__ rowptr,
                               int* __restrict__ cursor, int* __restrict__ csr_src,
                               int E, int N) {
    int i = blockIdx.x * 256 + threadIdx.x;
    if (i >= E + N) return;
    int s, d;
    if (i < E) { s = ei[i]; d = ei[E + i]; }
    else       { s = d = i - E; }
    int pos = atomicAdd(&cursor[d], 1);
    csr_src[rowptr[d] + pos] = s;
}

// ---------------- GEMM: h[n,128] = x[n,K] @ W[K,128] ----------------
template <int K>
__global__ void gemm_kernel(const float* __restrict__ x, const float* __restrict__ W,
                            float* __restrict__ h, int n) {
    const int ROWS = 16;
    __shared__ float xs[ROWS][K];
    int col  = threadIdx.x & 127;
    int half = threadIdx.x >> 7;  // 0..1
    int row0 = blockIdx.x * ROWS;

    for (int idx = threadIdx.x; idx < ROWS * K; idx += 256) {
        int rr = idx / K, kk = idx - rr * K;
        int gr = row0 + rr;
        xs[rr][kk] = (gr < n) ? x[(size_t)gr * K + kk] : 0.f;
    }
    __syncthreads();

    float acc[ROWS / 2];
#pragma unroll
    for (int i = 0; i < ROWS / 2; ++i) acc[i] = 0.f;

    for (int k = 0; k < K; ++k) {
        float wv = W[k * HC + col];
#pragma unroll
        for (int i = 0; i < ROWS / 2; ++i)
            acc[i] = fmaf(xs[2 * i + half][k], wv, acc[i]);
    }
#pragma unroll
    for (int i = 0; i < ROWS / 2; ++i) {
        int row = row0 + 2 * i + half;
        if (row < n) h[(size_t)row * HC + col] = acc[i];
    }
}

// ---------------- attention coefficients a_src/a_dst [N,H] ----------------
__global__ void att_kernel(const float* __restrict__ h, const float* __restrict__ as_,
                           const float* __restrict__ ad_, float* __restrict__ asrc,
                           float* __restrict__ adst, int n) {
    int i = blockIdx.x * 256 + threadIdx.x;  // i = node*H + head
    if (i >= n * H) return;
    int hd = i & (H - 1);
    const float4* hv = (const float4*)(h + (size_t)i * C);
    const float4* sv = (const float4*)(as_ + hd * C);
    const float4* dv = (const float4*)(ad_ + hd * C);
    float s = 0.f, d = 0.f;
#pragma unroll
    for (int j = 0; j < 4; ++j) {
        float4 a = hv[j], u = sv[j], v = dv[j];
        s += a.x * u.x + a.y * u.y + a.z * u.z + a.w * u.w;
        d += a.x * v.x + a.y * v.y + a.z * v.z + a.w * v.w;
    }
    asrc[i] = s;
    adst[i] = d;
}

// ---------------- fused GAT aggregation: one wave per destination ----------------
// lane = head*8 + channel_pair; softmax (max, exp-sum) + weighted gather + bias + relu
__global__ void gat_agg_kernel(const int* __restrict__ rowptr, const int* __restrict__ csr_src,
                               const float* __restrict__ h, const float* __restrict__ asrc,
                               const float* __restrict__ adst, const float* __restrict__ bias,
                               float* __restrict__ out, int N) {
    int dst = (blockIdx.x * 256 + threadIdx.x) >> 6;  // one wave per dst
    if (dst >= N) return;
    int lane = threadIdx.x & 63;
    int hd = lane >> 3;  // head for this lane's channels
    int beg = rowptr[dst], end = rowptr[dst + 1];
    float ad = adst[(size_t)dst * H + hd];

    float mx = -INFINITY;
    for (int j = beg; j < end; ++j) {
        int s = csr_src[j];
        float e = asrc[(size_t)s * H + hd] + ad;
        e = e > 0.f ? e : NEG_SLOPE * e;
        mx = fmaxf(mx, e);
    }
    float z = 0.f, a0 = 0.f, a1 = 0.f;
    for (int j = beg; j < end; ++j) {
        int s = csr_src[j];
        float e = asrc[(size_t)s * H + hd] + ad;
        e = e > 0.f ? e : NEG_SLOPE * e;
        float w = __expf(e - mx);
        z += w;
        float2 v = *(const float2*)(h + (size_t)s * HC + lane * 2);
        a0 = fmaf(w, v.x, a0);
        a1 = fmaf(w, v.y, a1);
    }
    float inv = 1.f / (z + 1e-16f);
    float r0 = fmaxf(fmaf(a0, inv, 0.f) + bias[lane * 2], 0.f);
    float r1 = fmaxf(fmaf(a1, inv, 0.f) + bias[lane * 2 + 1], 0.f);
    *(float2*)(out + (size_t)dst * HC + lane * 2) = make_float2(r0, r1);
}

// ---------------- global mean pool: one block (128 threads) per graph ----------------
__global__ void pool_kernel(const float* __restrict__ x, const int* __restrict__ gptr,
                            float* __restrict__ pooled, int G) {
    int g = blockIdx.x;
    int c = threadIdx.x;  // 0..127
    int beg = gptr[g], end = gptr[g + 1];
    float acc = 0.f;
    for (int n = beg; n < end; ++n) acc += x[(size_t)n * HC + c];
    pooled[(size_t)g * HC + c] = acc / fmaxf((float)(end - beg), 1.f);
}

// ---------------- final MLP: [G,128] -> relu(128->10) -> 10->1 ----------------
__global__ void mlp_kernel(const float* __restrict__ pooled,
                           const float* __restrict__ fc1w, const float* __restrict__ fc1b,
                           const float* __restrict__ fc2w, const float* __restrict__ fc2b,
                           float* __restrict__ out, int G) {
    int g = blockIdx.x * 64 + threadIdx.x;
    if (g >= G) return;
    float hdn[10];
#pragma unroll
    for (int j = 0; j < 10; ++j) hdn[j] = fc1b[j];
    for (int k = 0; k < HC; ++k) {
        float v = pooled[(size_t)g * HC + k];
#pragma unroll
        for (int j = 0; j < 10; ++j) hdn[j] = fmaf(v, fc1w[k * 10 + j], hdn[j]);
    }
    float acc = fc2b[0];
#pragma unroll
    for (int j = 0; j < 10; ++j) acc = fmaf(fmaxf(hdn[j], 0.f), fc2w[j], acc);
    out[g] = acc;
}

extern "C" void kernel_launch(void* const* d_in, const int* in_sizes, int n_in,
                              void* d_out, int out_size, void* d_ws, size_t ws_size,
                              hipStream_t stream) {
    const int N = in_sizes[0] / 64;   // 50000
    const int E = in_sizes[1] / 2;    // 600000
    const int G = out_size;           // 500
    const int ET = E + N;             // edges incl. self loops

    const float* x     = (const float*)d_in[0];
    const int*   ei    = (const int*)d_in[1];
    const int*   batch = (const int*)d_in[2];
    const float* W1 = (const float*)d_in[3];
    const float* as1 = (const float*)d_in[4];
    const float* ad1 = (const float*)d_in[5];
    const float* b1 = (const float*)d_in[6];
    const float* W2 = (const float*)d_in[7];
    const float* as2 = (const float*)d_in[8];
    const float* ad2 = (const float*)d_in[9];
    const float* b2 = (const float*)d_in[10];
    const float* W3 = (const float*)d_in[11];
    const float* as3 = (const float*)d_in[12];
    const float* ad3 = (const float*)d_in[13];
    const float* b3 = (const float*)d_in[14];
    const float* fc1w = (const float*)d_in[15];
    const float* fc1b = (const float*)d_in[16];
    const float* fc2w = (const float*)d_in[17];
    const float* fc2b = (const float*)d_in[18];

    // -------- workspace layout --------
    float* ws = (float*)d_ws;
    float* h      = ws;                          // N*128
    float* xb0    = h + (size_t)N * HC;          // N*128
    float* xb1    = xb0 + (size_t)N * HC;        // N*128
    float* asrc   = xb1 + (size_t)N * HC;        // N*8
    float* adst   = asrc + (size_t)N * H;        // N*8
    float* pooled = adst + (size_t)N * H;        // G*128
    int* ints   = (int*)(pooled + (size_t)G * HC);
    int* deg    = ints;                          // N
    int* cursor = deg + N;                       // N
    int* gcnt   = cursor + N;                    // G   (deg,cursor,gcnt contiguous -> one zero)
    int* rowptr = gcnt + G;                      // N+1
    int* gptr   = rowptr + N + 1;                // G+1
    int* csr    = gptr + G + 1;                  // ET

    dim3 blk(256);
    int grid_e   = (ET + 255) / 256;
    int grid_n   = (N + 255) / 256;
    int grid_agg = (N * 64 + 255) / 256;

    // -------- one-time CSR build (graph shared by all 3 layers) --------
    zero_int_kernel<<<(2 * N + G + 255) / 256, blk, 0, stream>>>(deg, 2 * N + G);
    hist_kernel<<<grid_e, blk, 0, stream>>>(ei, deg, E, N);
    batch_hist_kernel<<<grid_n, blk, 0, stream>>>(batch, gcnt, N);
    scan_kernel<<<1, 1024, 0, stream>>>(deg, rowptr, N);
    scan_kernel<<<1, 1024, 0, stream>>>(gcnt, gptr, G);
    scatter_kernel<<<grid_e, blk, 0, stream>>>(ei, rowptr, cursor, csr, E, N);

    auto run_layer = [&](const float* xin, int K, const float* W, const float* as_,
                         const float* ad_, const float* b, float* out) {
        if (K == 64)
            gemm_kernel<64><<<(N + 15) / 16, blk, 0, stream>>>(xin, W, h, N);
        else
            gemm_kernel<128><<<(N + 15) / 16, blk, 0, stream>>>(xin, W, h, N);
        att_kernel<<<(N * H + 255) / 256, blk, 0, stream>>>(h, as_, ad_, asrc, adst, N);
        gat_agg_kernel<<<grid_agg, blk, 0, stream>>>(rowptr, csr, h, asrc, adst, b, out, N);
    };

    run_layer(x,   64,  W1, as1, ad1, b1, xb0);
    run_layer(xb0, 128, W2, as2, ad2, b2, xb1);
    run_layer(xb1, 128, W3, as3, ad3, b3, xb0);

    pool_kernel<<<G, dim3(128), 0, stream>>>(xb0, gptr, pooled, G);
    mlp_kernel<<<(G + 63) / 64, dim3(64), 0, stream>>>(pooled, fc1w, fc1b, fc2w, fc2b,
                                                       (float*)d_out, G);
}

// Round 4
// 584.623 us; speedup vs baseline: 4.4238x; 1.1783x over previous
//
#include <hip/hip_runtime.h>
#include <hip/hip_bf16.h>

#define H 8
#define C 16
#define HC 128
#define NEG_SLOPE 0.2f

// ---------------- zero int region ----------------
__global__ void zero_int_kernel(int* __restrict__ p, int n) {
    int i = blockIdx.x * 256 + threadIdx.x;
    if (i < n) p[i] = 0;
}

// ---------------- degree histogram over dst (incl. self loops) ----------------
__global__ void hist_kernel(const int* __restrict__ ei, int* __restrict__ deg, int E, int N) {
    int i = blockIdx.x * 256 + threadIdx.x;
    if (i >= E + N) return;
    int d = (i < E) ? ei[E + i] : i - E;
    atomicAdd(&deg[d], 1);
}

// ---------------- batch histogram ----------------
__global__ void batch_hist_kernel(const int* __restrict__ batch, int* __restrict__ gcnt, int N) {
    int i = blockIdx.x * 256 + threadIdx.x;
    if (i >= N) return;
    atomicAdd(&gcnt[batch[i]], 1);
}

// ---------------- parallel exclusive scan: rowptr[0..n], one 1024-thread block ----
// per-thread sequential chunk reduce -> butterfly over thread totals -> write-back
__global__ void scan_kernel(const int* __restrict__ cnts, int* __restrict__ rowptr, int n) {
    __shared__ int sh[1024];
    int tid = threadIdx.x;
    int chunk = (n + 1023) / 1024;
    int b = tid * chunk;
    int e = min(b + chunk, n);
    int sum = 0;
    for (int i = b; i < e; ++i) sum += cnts[i];
    sh[tid] = sum;
    __syncthreads();
    for (int off = 1; off < 1024; off <<= 1) {
        int t = (tid >= off) ? sh[tid - off] : 0;
        __syncthreads();
        sh[tid] += t;
        __syncthreads();
    }
    int run = (tid > 0) ? sh[tid - 1] : 0;  // exclusive prefix of this thread's chunk
    for (int i = b; i < e; ++i) { rowptr[i] = run; run += cnts[i]; }
    if (tid == 1023) rowptr[n] = sh[1023];
}

// ---------------- scatter edges into CSR (by destination) ----------------
__global__ void scatter_kernel(const int* __restrict__ ei, const int* __restrict__ rowptr,
                               int* __restrict__ cursor, int* __restrict__ csr_src,
                               int E, int N) {
    int i = blockIdx.x * 256 + threadIdx.x;
    if (i >= E + N) return;
    int s, d;
    if (i < E) { s = ei[i]; d = ei[E + i]; }
    else       { s = d = i - E; }
    int pos = atomicAdd(&cursor[d], 1);
    csr_src[rowptr[d] + pos] = s;
}

// ---------------- GEMM: h[n,128] = x[n,K] @ W[K,128] ----------------
template <int K>
__global__ void gemm_kernel(const float* __restrict__ x, const float* __restrict__ W,
                            float* __restrict__ h, int n) {
    const int ROWS = 16;
    __shared__ float xs[ROWS][K];
    int col  = threadIdx.x & 127;
    int half = threadIdx.x >> 7;  // 0..1
    int row0 = blockIdx.x * ROWS;

    for (int idx = threadIdx.x; idx < ROWS * K; idx += 256) {
        int rr = idx / K, kk = idx - rr * K;
        int gr = row0 + rr;
        xs[rr][kk] = (gr < n) ? x[(size_t)gr * K + kk] : 0.f;
    }
    __syncthreads();

    float acc[ROWS / 2];
#pragma unroll
    for (int i = 0; i < ROWS / 2; ++i) acc[i] = 0.f;

    for (int k = 0; k < K; ++k) {
        float wv = W[k * HC + col];
#pragma unroll
        for (int i = 0; i < ROWS / 2; ++i)
            acc[i] = fmaf(xs[2 * i + half][k], wv, acc[i]);
    }
#pragma unroll
    for (int i = 0; i < ROWS / 2; ++i) {
        int row = row0 + 2 * i + half;
        if (row < n) h[(size_t)row * HC + col] = acc[i];
    }
}

// ---------------- attention coefficients a_src/a_dst [N,H] ----------------
__global__ void att_kernel(const float* __restrict__ h, const float* __restrict__ as_,
                           const float* __restrict__ ad_, float* __restrict__ asrc,
                           float* __restrict__ adst, int n) {
    int i = blockIdx.x * 256 + threadIdx.x;  // i = node*H + head
    if (i >= n * H) return;
    int hd = i & (H - 1);
    const float4* hv = (const float4*)(h + (size_t)i * C);
    const float4* sv = (const float4*)(as_ + hd * C);
    const float4* dv = (const float4*)(ad_ + hd * C);
    float s = 0.f, d = 0.f;
#pragma unroll
    for (int j = 0; j < 4; ++j) {
        float4 a = hv[j], u = sv[j], v = dv[j];
        s += a.x * u.x + a.y * u.y + a.z * u.z + a.w * u.w;
        d += a.x * v.x + a.y * v.y + a.z * v.z + a.w * v.w;
    }
    asrc[i] = s;
    adst[i] = d;
}

// ---------------- fused GAT aggregation: one wave per destination ----------------
// Single-pass online softmax, software-pipelined edge loop.
// lane = head*8 + channel_pair; iter j processes edge j-1 while loading edge j.
__global__ void gat_agg_kernel(const int* __restrict__ rowptr, const int* __restrict__ csr_src,
                               const float* __restrict__ h, const float* __restrict__ asrc,
                               const float* __restrict__ adst, const float* __restrict__ bias,
                               float* __restrict__ out, int N) {
    int dst = (blockIdx.x * 256 + threadIdx.x) >> 6;  // one wave per dst
    if (dst >= N) return;
    int lane = threadIdx.x & 63;
    int hd = lane >> 3;  // head for this lane's channels
    int beg = rowptr[dst], end = rowptr[dst + 1];
    float ad = adst[(size_t)dst * H + hd];
    const float2* h2 = (const float2*)h;  // row stride = 64 float2

    float m = -INFINITY, z = 0.f, a0 = 0.f, a1 = 0.f;
    if (beg < end) {
        int s0 = csr_src[beg];
        float e0 = asrc[(size_t)s0 * H + hd];
        float2 v0 = h2[(size_t)s0 * 64 + lane];
        for (int j = beg + 1; j <= end; ++j) {
            // ---- issue next edge's loads (independent of the math below) ----
            int jn = (j < end) ? j : end - 1;
            int s1 = csr_src[jn];
            float e1 = asrc[(size_t)s1 * H + hd];
            float2 v1 = h2[(size_t)s1 * 64 + lane];
            // ---- process previous edge (data already in registers) ----
            float e = e0 + ad;
            e = e > 0.f ? e : NEG_SLOPE * e;
            float mn = fmaxf(m, e);
            float corr = __expf(m - mn);   // 0 on first iter (m = -inf)
            float w = __expf(e - mn);
            m = mn;
            z  = fmaf(z,  corr, w);
            a0 = fmaf(a0, corr, w * v0.x);
            a1 = fmaf(a1, corr, w * v0.y);
            e0 = e1; v0 = v1;
        }
    }
    float inv = 1.f / (z + 1e-16f);
    int c2 = lane * 2;
    float r0 = fmaxf(a0 * inv + bias[c2], 0.f);
    float r1 = fmaxf(a1 * inv + bias[c2 + 1], 0.f);
    *(float2*)(out + (size_t)dst * HC + c2) = make_float2(r0, r1);
}

// ---------------- global mean pool: one block (128 threads) per graph ----------------
__global__ void pool_kernel(const float* __restrict__ x, const int* __restrict__ gptr,
                            float* __restrict__ pooled, int G) {
    int g = blockIdx.x;
    int c = threadIdx.x;  // 0..127
    int beg = gptr[g], end = gptr[g + 1];
    float acc = 0.f;
    for (int n = beg; n < end; ++n) acc += x[(size_t)n * HC + c];
    pooled[(size_t)g * HC + c] = acc / fmaxf((float)(end - beg), 1.f);
}

// ---------------- final MLP: [G,128] -> relu(128->10) -> 10->1 ----------------
__global__ void mlp_kernel(const float* __restrict__ pooled,
                           const float* __restrict__ fc1w, const float* __restrict__ fc1b,
                           const float* __restrict__ fc2w, const float* __restrict__ fc2b,
                           float* __restrict__ out, int G) {
    int g = blockIdx.x * 64 + threadIdx.x;
    if (g >= G) return;
    float hdn[10];
#pragma unroll
    for (int j = 0; j < 10; ++j) hdn[j] = fc1b[j];
    for (int k = 0; k < HC; ++k) {
        float v = pooled[(size_t)g * HC + k];
#pragma unroll
        for (int j = 0; j < 10; ++j) hdn[j] = fmaf(v, fc1w[k * 10 + j], hdn[j]);
    }
    float acc = fc2b[0];
#pragma unroll
    for (int j = 0; j < 10; ++j) acc = fmaf(fmaxf(hdn[j], 0.f), fc2w[j], acc);
    out[g] = acc;
}

extern "C" void kernel_launch(void* const* d_in, const int* in_sizes, int n_in,
                              void* d_out, int out_size, void* d_ws, size_t ws_size,
                              hipStream_t stream) {
    const int N = in_sizes[0] / 64;   // 50000
    const int E = in_sizes[1] / 2;    // 600000
    const int G = out_size;           // 500
    const int ET = E + N;             // edges incl. self loops

    const float* x     = (const float*)d_in[0];
    const int*   ei    = (const int*)d_in[1];
    const int*   batch = (const int*)d_in[2];
    const float* W1 = (const float*)d_in[3];
    const float* as1 = (const float*)d_in[4];
    const float* ad1 = (const float*)d_in[5];
    const float* b1 = (const float*)d_in[6];
    const float* W2 = (const float*)d_in[7];
    const float* as2 = (const float*)d_in[8];
    const float* ad2 = (const float*)d_in[9];
    const float* b2 = (const float*)d_in[10];
    const float* W3 = (const float*)d_in[11];
    const float* as3 = (const float*)d_in[12];
    const float* ad3 = (const float*)d_in[13];
    const float* b3 = (const float*)d_in[14];
    const float* fc1w = (const float*)d_in[15];
    const float* fc1b = (const float*)d_in[16];
    const float* fc2w = (const float*)d_in[17];
    const float* fc2b = (const float*)d_in[18];

    // -------- workspace layout --------
    float* ws = (float*)d_ws;
    float* h      = ws;                          // N*128
    float* xb0    = h + (size_t)N * HC;          // N*128
    float* xb1    = xb0 + (size_t)N * HC;        // N*128
    float* asrc   = xb1 + (size_t)N * HC;        // N*8
    float* adst   = asrc + (size_t)N * H;        // N*8
    float* pooled = adst + (size_t)N * H;        // G*128
    int* ints   = (int*)(pooled + (size_t)G * HC);
    int* deg    = ints;                          // N
    int* cursor = deg + N;                       // N
    int* gcnt   = cursor + N;                    // G   (deg,cursor,gcnt contiguous -> one zero)
    int* rowptr = gcnt + G;                      // N+1
    int* gptr   = rowptr + N + 1;                // G+1
    int* csr    = gptr + G + 1;                  // ET

    dim3 blk(256);
    int grid_e   = (ET + 255) / 256;
    int grid_n   = (N + 255) / 256;
    int grid_agg = (N * 64 + 255) / 256;

    // -------- one-time CSR build (graph shared by all 3 layers) --------
    zero_int_kernel<<<(2 * N + G + 255) / 256, blk, 0, stream>>>(deg, 2 * N + G);
    hist_kernel<<<grid_e, blk, 0, stream>>>(ei, deg, E, N);
    batch_hist_kernel<<<grid_n, blk, 0, stream>>>(batch, gcnt, N);
    scan_kernel<<<1, 1024, 0, stream>>>(deg, rowptr, N);
    scan_kernel<<<1, 1024, 0, stream>>>(gcnt, gptr, G);
    scatter_kernel<<<grid_e, blk, 0, stream>>>(ei, rowptr, cursor, csr, E, N);

    auto run_layer = [&](const float* xin, int K, const float* W, const float* as_,
                         const float* ad_, const float* b, float* out) {
        if (K == 64)
            gemm_kernel<64><<<(N + 15) / 16, blk, 0, stream>>>(xin, W, h, N);
        else
            gemm_kernel<128><<<(N + 15) / 16, blk, 0, stream>>>(xin, W, h, N);
        att_kernel<<<(N * H + 255) / 256, blk, 0, stream>>>(h, as_, ad_, asrc, adst, N);
        gat_agg_kernel<<<grid_agg, blk, 0, stream>>>(rowptr, csr, h, asrc, adst, b, out, N);
    };

    run_layer(x,   64,  W1, as1, ad1, b1, xb0);
    run_layer(xb0, 128, W2, as2, ad2, b2, xb1);
    run_layer(xb1, 128, W3, as3, ad3, b3, xb0);

    pool_kernel<<<G, dim3(128), 0, stream>>>(xb0, gptr, pooled, G);
    mlp_kernel<<<(G + 63) / 64, dim3(64), 0, stream>>>(pooled, fc1w, fc1b, fc2w, fc2b,
                                                       (float*)d_out, G);
}

// Round 5
// 516.164 us; speedup vs baseline: 5.0105x; 1.1326x over previous
//
#include <hip/hip_runtime.h>
#include <hip/hip_bf16.h>

#define H 8
#define C 16
#define HC 128
#define NEG_SLOPE 0.2f

// ---------------- zero int region ----------------
__global__ void zero_int_kernel(int* __restrict__ p, int n) {
    int i = blockIdx.x * 256 + threadIdx.x;
    if (i < n) p[i] = 0;
}

// ---------------- degree histogram over dst (incl. self loops) ----------------
__global__ void hist_kernel(const int* __restrict__ ei, int* __restrict__ deg, int E, int N) {
    int i = blockIdx.x * 256 + threadIdx.x;
    if (i >= E + N) return;
    int d = (i < E) ? ei[E + i] : i - E;
    atomicAdd(&deg[d], 1);
}

// ---------------- batch histogram ----------------
__global__ void batch_hist_kernel(const int* __restrict__ batch, int* __restrict__ gcnt, int N) {
    int i = blockIdx.x * 256 + threadIdx.x;
    if (i >= N) return;
    atomicAdd(&gcnt[batch[i]], 1);
}

// ---------------- parallel exclusive scan: rowptr[0..n], one 1024-thread block ----
__global__ void scan_kernel(const int* __restrict__ cnts, int* __restrict__ rowptr, int n) {
    __shared__ int sh[1024];
    int tid = threadIdx.x;
    int chunk = (n + 1023) / 1024;
    int b = tid * chunk;
    int e = min(b + chunk, n);
    int sum = 0;
    for (int i = b; i < e; ++i) sum += cnts[i];
    sh[tid] = sum;
    __syncthreads();
    for (int off = 1; off < 1024; off <<= 1) {
        int t = (tid >= off) ? sh[tid - off] : 0;
        __syncthreads();
        sh[tid] += t;
        __syncthreads();
    }
    int run = (tid > 0) ? sh[tid - 1] : 0;  // exclusive prefix of this thread's chunk
    for (int i = b; i < e; ++i) { rowptr[i] = run; run += cnts[i]; }
    if (tid == 1023) rowptr[n] = sh[1023];
}

// ---------------- scatter edges into CSR (by destination) ----------------
__global__ void scatter_kernel(const int* __restrict__ ei, const int* __restrict__ rowptr,
                               int* __restrict__ cursor, int* __restrict__ csr_src,
                               int E, int N) {
    int i = blockIdx.x * 256 + threadIdx.x;
    if (i >= E + N) return;
    int s, d;
    if (i < E) { s = ei[i]; d = ei[E + i]; }
    else       { s = d = i - E; }
    int pos = atomicAdd(&cursor[d], 1);
    csr_src[rowptr[d] + pos] = s;
}

// ---------------- GEMM: h[n,128] = x[n,K] @ W[K,128] ----------------
// 32x128 tile, 256 threads, each thread 4 rows x 4 cols, k unrolled by 4.
template <int K>
__global__ void gemm_kernel(const float* __restrict__ x, const float* __restrict__ W,
                            float* __restrict__ h, int n) {
    const int ROWS = 32;
    __shared__ float xs[ROWS][K];  // row-major; float4-aligned rows (K % 4 == 0)
    int tx = threadIdx.x & 31;     // col group: cols tx*4 .. tx*4+3
    int ty = threadIdx.x >> 5;     // row group: rows ty*4 .. ty*4+3
    int row0 = blockIdx.x * ROWS;

    // stage x tile as float4
    const int NV = ROWS * K / 4;  // float4 count
    for (int idx = threadIdx.x; idx < NV; idx += 256) {
        int rr = idx / (K / 4), kk = idx % (K / 4);
        int gr = row0 + rr;
        float4 v = (gr < n) ? ((const float4*)(x + (size_t)gr * K))[kk]
                            : make_float4(0.f, 0.f, 0.f, 0.f);
        ((float4*)&xs[rr][0])[kk] = v;
    }
    __syncthreads();

    const float* Wc = W + tx * 4;
    float acc[4][4];
#pragma unroll
    for (int r = 0; r < 4; ++r)
#pragma unroll
        for (int c = 0; c < 4; ++c) acc[r][c] = 0.f;

    for (int k = 0; k < K; k += 4) {
        float4 xr[4];
#pragma unroll
        for (int r = 0; r < 4; ++r)
            xr[r] = *(const float4*)(&xs[ty * 4 + r][k]);
        float4 wv[4];
#pragma unroll
        for (int kk = 0; kk < 4; ++kk)
            wv[kk] = *(const float4*)(Wc + (size_t)(k + kk) * HC);
#pragma unroll
        for (int r = 0; r < 4; ++r) {
            acc[r][0] = fmaf(xr[r].x, wv[0].x, acc[r][0]);
            acc[r][1] = fmaf(xr[r].x, wv[0].y, acc[r][1]);
            acc[r][2] = fmaf(xr[r].x, wv[0].z, acc[r][2]);
            acc[r][3] = fmaf(xr[r].x, wv[0].w, acc[r][3]);
            acc[r][0] = fmaf(xr[r].y, wv[1].x, acc[r][0]);
            acc[r][1] = fmaf(xr[r].y, wv[1].y, acc[r][1]);
            acc[r][2] = fmaf(xr[r].y, wv[1].z, acc[r][2]);
            acc[r][3] = fmaf(xr[r].y, wv[1].w, acc[r][3]);
            acc[r][0] = fmaf(xr[r].z, wv[2].x, acc[r][0]);
            acc[r][1] = fmaf(xr[r].z, wv[2].y, acc[r][1]);
            acc[r][2] = fmaf(xr[r].z, wv[2].z, acc[r][2]);
            acc[r][3] = fmaf(xr[r].z, wv[2].w, acc[r][3]);
            acc[r][0] = fmaf(xr[r].w, wv[3].x, acc[r][0]);
            acc[r][1] = fmaf(xr[r].w, wv[3].y, acc[r][1]);
            acc[r][2] = fmaf(xr[r].w, wv[3].z, acc[r][2]);
            acc[r][3] = fmaf(xr[r].w, wv[3].w, acc[r][3]);
        }
    }
#pragma unroll
    for (int r = 0; r < 4; ++r) {
        int row = row0 + ty * 4 + r;
        if (row < n)
            *(float4*)(h + (size_t)row * HC + tx * 4) =
                make_float4(acc[r][0], acc[r][1], acc[r][2], acc[r][3]);
    }
}

// ---------------- attention coefficients a_src/a_dst [N,H] ----------------
__global__ void att_kernel(const float* __restrict__ h, const float* __restrict__ as_,
                           const float* __restrict__ ad_, float* __restrict__ asrc,
                           float* __restrict__ adst, int n) {
    int i = blockIdx.x * 256 + threadIdx.x;  // i = node*H + head
    if (i >= n * H) return;
    int hd = i & (H - 1);
    const float4* hv = (const float4*)(h + (size_t)i * C);
    const float4* sv = (const float4*)(as_ + hd * C);
    const float4* dv = (const float4*)(ad_ + hd * C);
    float s = 0.f, d = 0.f;
#pragma unroll
    for (int j = 0; j < 4; ++j) {
        float4 a = hv[j], u = sv[j], v = dv[j];
        s += a.x * u.x + a.y * u.y + a.z * u.z + a.w * u.w;
        d += a.x * v.x + a.y * v.y + a.z * v.z + a.w * v.w;
    }
    asrc[i] = s;
    adst[i] = d;
}

// ---------------- fused GAT aggregation: one wave per destination ----------------
// Single-pass online softmax, 4-deep software pipeline (named register slots).
__global__ void gat_agg_kernel(const int* __restrict__ rowptr, const int* __restrict__ csr_src,
                               const float* __restrict__ h, const float* __restrict__ asrc,
                               const float* __restrict__ adst, const float* __restrict__ bias,
                               float* __restrict__ out, int N) {
    int dst = (blockIdx.x * 256 + threadIdx.x) >> 6;  // one wave per dst
    if (dst >= N) return;
    int lane = threadIdx.x & 63;
    int hd = lane >> 3;
    int beg = rowptr[dst], end = rowptr[dst + 1];
    int endm1 = end - 1;
    float ad = adst[(size_t)dst * H + hd];
    const float2* h2 = (const float2*)h;  // row stride = 64 float2

    float m = -INFINITY, z = 0.f, a0 = 0.f, a1 = 0.f;
    if (beg < end) {
#define LOADE(S, J)                                                        \
        { int _j = (J); _j = _j < endm1 ? _j : endm1; int _s = csr_src[_j]; \
          e##S = asrc[(size_t)_s * H + hd]; v##S = h2[(size_t)_s * 64 + lane]; }
#define PROCE(S, J)                                                        \
        if ((J) < end) {                                                   \
            float e = e##S + ad;                                           \
            e = e > 0.f ? e : NEG_SLOPE * e;                               \
            float mn = fmaxf(m, e);                                        \
            float corr = __expf(m - mn);                                   \
            float w = __expf(e - mn);                                      \
            m = mn;                                                        \
            z  = fmaf(z,  corr, w);                                        \
            a0 = fmaf(a0, corr, w * v##S.x);                               \
            a1 = fmaf(a1, corr, w * v##S.y);                               \
        }
        float e0, e1, e2, e3;
        float2 v0, v1, v2, v3;
        LOADE(0, beg) LOADE(1, beg + 1) LOADE(2, beg + 2) LOADE(3, beg + 3)
        for (int j = beg; j < end; j += 4) {
            PROCE(0, j)     LOADE(0, j + 4)
            PROCE(1, j + 1) LOADE(1, j + 5)
            PROCE(2, j + 2) LOADE(2, j + 6)
            PROCE(3, j + 3) LOADE(3, j + 7)
        }
#undef LOADE
#undef PROCE
    }
    float inv = 1.f / (z + 1e-16f);
    int c2 = lane * 2;
    float r0 = fmaxf(a0 * inv + bias[c2], 0.f);
    float r1 = fmaxf(a1 * inv + bias[c2 + 1], 0.f);
    *(float2*)(out + (size_t)dst * HC + c2) = make_float2(r0, r1);
}

// ---------------- global mean pool: one block (128 threads) per graph ----------------
__global__ void pool_kernel(const float* __restrict__ x, const int* __restrict__ gptr,
                            float* __restrict__ pooled, int G) {
    int g = blockIdx.x;
    int c = threadIdx.x;  // 0..127
    int beg = gptr[g], end = gptr[g + 1];
    float acc = 0.f;
    for (int n = beg; n < end; ++n) acc += x[(size_t)n * HC + c];
    pooled[(size_t)g * HC + c] = acc / fmaxf((float)(end - beg), 1.f);
}

// ---------------- final MLP: [G,128] -> relu(128->10) -> 10->1 ----------------
__global__ void mlp_kernel(const float* __restrict__ pooled,
                           const float* __restrict__ fc1w, const float* __restrict__ fc1b,
                           const float* __restrict__ fc2w, const float* __restrict__ fc2b,
                           float* __restrict__ out, int G) {
    int g = blockIdx.x * 64 + threadIdx.x;
    if (g >= G) return;
    float hdn[10];
#pragma unroll
    for (int j = 0; j < 10; ++j) hdn[j] = fc1b[j];
    for (int k = 0; k < HC; ++k) {
        float v = pooled[(size_t)g * HC + k];
#pragma unroll
        for (int j = 0; j < 10; ++j) hdn[j] = fmaf(v, fc1w[k * 10 + j], hdn[j]);
    }
    float acc = fc2b[0];
#pragma unroll
    for (int j = 0; j < 10; ++j) acc = fmaf(fmaxf(hdn[j], 0.f), fc2w[j], acc);
    out[g] = acc;
}

extern "C" void kernel_launch(void* const* d_in, const int* in_sizes, int n_in,
                              void* d_out, int out_size, void* d_ws, size_t ws_size,
                              hipStream_t stream) {
    const int N = in_sizes[0] / 64;   // 50000
    const int E = in_sizes[1] / 2;    // 600000
    const int G = out_size;           // 500
    const int ET = E + N;             // edges incl. self loops

    const float* x     = (const float*)d_in[0];
    const int*   ei    = (const int*)d_in[1];
    const int*   batch = (const int*)d_in[2];
    const float* W1 = (const float*)d_in[3];
    const float* as1 = (const float*)d_in[4];
    const float* ad1 = (const float*)d_in[5];
    const float* b1 = (const float*)d_in[6];
    const float* W2 = (const float*)d_in[7];
    const float* as2 = (const float*)d_in[8];
    const float* ad2 = (const float*)d_in[9];
    const float* b2 = (const float*)d_in[10];
    const float* W3 = (const float*)d_in[11];
    const float* as3 = (const float*)d_in[12];
    const float* ad3 = (const float*)d_in[13];
    const float* b3 = (const float*)d_in[14];
    const float* fc1w = (const float*)d_in[15];
    const float* fc1b = (const float*)d_in[16];
    const float* fc2w = (const float*)d_in[17];
    const float* fc2b = (const float*)d_in[18];

    // -------- workspace layout --------
    float* ws = (float*)d_ws;
    float* h      = ws;                          // N*128
    float* xb0    = h + (size_t)N * HC;          // N*128
    float* xb1    = xb0 + (size_t)N * HC;        // N*128
    float* asrc   = xb1 + (size_t)N * HC;        // N*8
    float* adst   = asrc + (size_t)N * H;        // N*8
    float* pooled = adst + (size_t)N * H;        // G*128
    int* ints   = (int*)(pooled + (size_t)G * HC);
    int* deg    = ints;                          // N
    int* cursor = deg + N;                       // N
    int* gcnt   = cursor + N;                    // G
    int* rowptr = gcnt + G;                      // N+1
    int* gptr   = rowptr + N + 1;                // G+1
    int* csr    = gptr + G + 1;                  // ET

    dim3 blk(256);
    int grid_e   = (ET + 255) / 256;
    int grid_n   = (N + 255) / 256;
    int grid_agg = (N * 64 + 255) / 256;

    // -------- one-time CSR build (graph shared by all 3 layers) --------
    zero_int_kernel<<<(2 * N + G + 255) / 256, blk, 0, stream>>>(deg, 2 * N + G);
    hist_kernel<<<grid_e, blk, 0, stream>>>(ei, deg, E, N);
    batch_hist_kernel<<<grid_n, blk, 0, stream>>>(batch, gcnt, N);
    scan_kernel<<<1, 1024, 0, stream>>>(deg, rowptr, N);
    scan_kernel<<<1, 1024, 0, stream>>>(gcnt, gptr, G);
    scatter_kernel<<<grid_e, blk, 0, stream>>>(ei, rowptr, cursor, csr, E, N);

    auto run_layer = [&](const float* xin, int K, const float* W, const float* as_,
                         const float* ad_, const float* b, float* out) {
        if (K == 64)
            gemm_kernel<64><<<(N + 31) / 32, blk, 0, stream>>>(xin, W, h, N);
        else
            gemm_kernel<128><<<(N + 31) / 32, blk, 0, stream>>>(xin, W, h, N);
        att_kernel<<<(N * H + 255) / 256, blk, 0, stream>>>(h, as_, ad_, asrc, adst, N);
        gat_agg_kernel<<<grid_agg, blk, 0, stream>>>(rowptr, csr, h, asrc, adst, b, out, N);
    };

    run_layer(x,   64,  W1, as1, ad1, b1, xb0);
    run_layer(xb0, 128, W2, as2, ad2, b2, xb1);
    run_layer(xb1, 128, W3, as3, ad3, b3, xb0);

    pool_kernel<<<G, dim3(128), 0, stream>>>(xb0, gptr, pooled, G);
    mlp_kernel<<<(G + 63) / 64, dim3(64), 0, stream>>>(pooled, fc1w, fc1b, fc2w, fc2b,
                                                       (float*)d_out, G);
}

// Round 6
// 483.345 us; speedup vs baseline: 5.3508x; 1.0679x over previous
//
#include <hip/hip_runtime.h>
#include <hip/hip_bf16.h>

#define H 8
#define C 16
#define HC 128
#define NEG_SLOPE 0.2f

// ---------------- zero int region ----------------
__global__ void zero_int_kernel(int* __restrict__ p, int n) {
    int i = blockIdx.x * 256 + threadIdx.x;
    if (i < n) p[i] = 0;
}

// ---------------- degree histogram over dst (incl. self loops) ----------------
__global__ void hist_kernel(const int* __restrict__ ei, int* __restrict__ deg, int E, int N) {
    int i = blockIdx.x * 256 + threadIdx.x;
    if (i >= E + N) return;
    int d = (i < E) ? ei[E + i] : i - E;
    atomicAdd(&deg[d], 1);
}

// ---------------- batch histogram ----------------
__global__ void batch_hist_kernel(const int* __restrict__ batch, int* __restrict__ gcnt, int N) {
    int i = blockIdx.x * 256 + threadIdx.x;
    if (i >= N) return;
    atomicAdd(&gcnt[batch[i]], 1);
}

// ======== 3-phase coalesced exclusive scan ========
// phase 1: each block scans a 1024-elem chunk (int4 per thread), writes partial
__global__ void scan_blk_kernel(const int* __restrict__ cnts, int* __restrict__ out,
                                int* __restrict__ partials, int n) {
    __shared__ int sh[256];
    int tid = threadIdx.x;
    int base = blockIdx.x * 1024 + tid * 4;
    int4 v = make_int4(0, 0, 0, 0);
    if (base + 3 < n) v = *(const int4*)(cnts + base);
    else {
        if (base < n)     v.x = cnts[base];
        if (base + 1 < n) v.y = cnts[base + 1];
        if (base + 2 < n) v.z = cnts[base + 2];
        if (base + 3 < n) v.w = cnts[base + 3];
    }
    int s = v.x + v.y + v.z + v.w;
    sh[tid] = s;
    __syncthreads();
    for (int off = 1; off < 256; off <<= 1) {
        int t = (tid >= off) ? sh[tid - off] : 0;
        __syncthreads();
        sh[tid] += t;
        __syncthreads();
    }
    int excl = sh[tid] - s;
    int4 o;
    o.x = excl;
    o.y = o.x + v.x;
    o.z = o.y + v.y;
    o.w = o.z + v.z;
    if (base + 3 < n) *(int4*)(out + base) = o;
    else {
        if (base < n)     out[base] = o.x;
        if (base + 1 < n) out[base + 1] = o.y;
        if (base + 2 < n) out[base + 2] = o.z;
        if (base + 3 < n) out[base + 3] = o.w;
    }
    if (tid == 255) partials[blockIdx.x] = sh[255];
}

// phase 2: exclusive-scan the block partials (nb <= 256), write grand total
__global__ void scan_part_kernel(int* __restrict__ partials, int* __restrict__ total_out, int nb) {
    __shared__ int sh[256];
    int tid = threadIdx.x;
    int v = (tid < nb) ? partials[tid] : 0;
    sh[tid] = v;
    __syncthreads();
    for (int off = 1; off < 256; off <<= 1) {
        int t = (tid >= off) ? sh[tid - off] : 0;
        __syncthreads();
        sh[tid] += t;
        __syncthreads();
    }
    if (tid < nb) partials[tid] = sh[tid] - v;  // exclusive
    if (tid == 255) *total_out = sh[255];
}

// phase 3: add block offsets
__global__ void scan_add_kernel(int* __restrict__ out, const int* __restrict__ partials, int n) {
    int tid = threadIdx.x;
    int off = partials[blockIdx.x];
    int base = blockIdx.x * 1024 + tid * 4;
    if (base + 3 < n) {
        int4 v = *(const int4*)(out + base);
        v.x += off; v.y += off; v.z += off; v.w += off;
        *(int4*)(out + base) = v;
    } else {
        if (base < n)     out[base] += off;
        if (base + 1 < n) out[base + 1] += off;
        if (base + 2 < n) out[base + 2] += off;
        if (base + 3 < n) out[base + 3] += off;
    }
}

// ---------------- scatter edges into CSR (by destination) ----------------
__global__ void scatter_kernel(const int* __restrict__ ei, const int* __restrict__ rowptr,
                               int* __restrict__ cursor, int* __restrict__ csr_src,
                               int E, int N) {
    int i = blockIdx.x * 256 + threadIdx.x;
    if (i >= E + N) return;
    int s, d;
    if (i < E) { s = ei[i]; d = ei[E + i]; }
    else       { s = d = i - E; }
    int pos = atomicAdd(&cursor[d], 1);
    csr_src[rowptr[d] + pos] = s;
}

// ---------------- GEMM: h[n,128] = x[n,K] @ W[K,128] ----------------
// 32x128 tile, 256 threads, each thread 4 rows x 4 cols, k unrolled by 4.
template <int K>
__global__ void gemm_kernel(const float* __restrict__ x, const float* __restrict__ W,
                            float* __restrict__ h, int n) {
    const int ROWS = 32;
    __shared__ float xs[ROWS][K];
    int tx = threadIdx.x & 31;
    int ty = threadIdx.x >> 5;
    int row0 = blockIdx.x * ROWS;

    const int NV = ROWS * K / 4;
    for (int idx = threadIdx.x; idx < NV; idx += 256) {
        int rr = idx / (K / 4), kk = idx % (K / 4);
        int gr = row0 + rr;
        float4 v = (gr < n) ? ((const float4*)(x + (size_t)gr * K))[kk]
                            : make_float4(0.f, 0.f, 0.f, 0.f);
        ((float4*)&xs[rr][0])[kk] = v;
    }
    __syncthreads();

    const float* Wc = W + tx * 4;
    float acc[4][4];
#pragma unroll
    for (int r = 0; r < 4; ++r)
#pragma unroll
        for (int c = 0; c < 4; ++c) acc[r][c] = 0.f;

    for (int k = 0; k < K; k += 4) {
        float4 xr[4];
#pragma unroll
        for (int r = 0; r < 4; ++r)
            xr[r] = *(const float4*)(&xs[ty * 4 + r][k]);
        float4 wv[4];
#pragma unroll
        for (int kk = 0; kk < 4; ++kk)
            wv[kk] = *(const float4*)(Wc + (size_t)(k + kk) * HC);
#pragma unroll
        for (int r = 0; r < 4; ++r) {
            acc[r][0] = fmaf(xr[r].x, wv[0].x, acc[r][0]);
            acc[r][1] = fmaf(xr[r].x, wv[0].y, acc[r][1]);
            acc[r][2] = fmaf(xr[r].x, wv[0].z, acc[r][2]);
            acc[r][3] = fmaf(xr[r].x, wv[0].w, acc[r][3]);
            acc[r][0] = fmaf(xr[r].y, wv[1].x, acc[r][0]);
            acc[r][1] = fmaf(xr[r].y, wv[1].y, acc[r][1]);
            acc[r][2] = fmaf(xr[r].y, wv[1].z, acc[r][2]);
            acc[r][3] = fmaf(xr[r].y, wv[1].w, acc[r][3]);
            acc[r][0] = fmaf(xr[r].z, wv[2].x, acc[r][0]);
            acc[r][1] = fmaf(xr[r].z, wv[2].y, acc[r][1]);
            acc[r][2] = fmaf(xr[r].z, wv[2].z, acc[r][2]);
            acc[r][3] = fmaf(xr[r].z, wv[2].w, acc[r][3]);
            acc[r][0] = fmaf(xr[r].w, wv[3].x, acc[r][0]);
            acc[r][1] = fmaf(xr[r].w, wv[3].y, acc[r][1]);
            acc[r][2] = fmaf(xr[r].w, wv[3].z, acc[r][2]);
            acc[r][3] = fmaf(xr[r].w, wv[3].w, acc[r][3]);
        }
    }
#pragma unroll
    for (int r = 0; r < 4; ++r) {
        int row = row0 + ty * 4 + r;
        if (row < n)
            *(float4*)(h + (size_t)row * HC + tx * 4) =
                make_float4(acc[r][0], acc[r][1], acc[r][2], acc[r][3]);
    }
}

// ---------------- attention coefficients a_src/a_dst [N,H] ----------------
__global__ void att_kernel(const float* __restrict__ h, const float* __restrict__ as_,
                           const float* __restrict__ ad_, float* __restrict__ asrc,
                           float* __restrict__ adst, int n) {
    int i = blockIdx.x * 256 + threadIdx.x;
    if (i >= n * H) return;
    int hd = i & (H - 1);
    const float4* hv = (const float4*)(h + (size_t)i * C);
    const float4* sv = (const float4*)(as_ + hd * C);
    const float4* dv = (const float4*)(ad_ + hd * C);
    float s = 0.f, d = 0.f;
#pragma unroll
    for (int j = 0; j < 4; ++j) {
        float4 a = hv[j], u = sv[j], v = dv[j];
        s += a.x * u.x + a.y * u.y + a.z * u.z + a.w * u.w;
        d += a.x * v.x + a.y * v.y + a.z * v.z + a.w * v.w;
    }
    asrc[i] = s;
    adst[i] = d;
}

// ---------------- fused GAT aggregation: one wave per destination ----------------
// Single-pass online softmax, 8-deep software pipeline (named register slots).
__global__ void gat_agg_kernel(const int* __restrict__ rowptr, const int* __restrict__ csr_src,
                               const float* __restrict__ h, const float* __restrict__ asrc,
                               const float* __restrict__ adst, const float* __restrict__ bias,
                               float* __restrict__ out, int N) {
    int dst = (blockIdx.x * 256 + threadIdx.x) >> 6;  // one wave per dst
    if (dst >= N) return;
    int lane = threadIdx.x & 63;
    int hd = lane >> 3;
    int beg = rowptr[dst], end = rowptr[dst + 1];
    int endm1 = end - 1;
    float ad = adst[(size_t)dst * H + hd];
    const float2* h2 = (const float2*)h;  // row stride = 64 float2

    float m = -INFINITY, z = 0.f, a0 = 0.f, a1 = 0.f;
    if (beg < end) {
#define LOADE(S, J)                                                        \
        { int _j = (J); _j = _j < endm1 ? _j : endm1; int _s = csr_src[_j]; \
          e##S = asrc[(size_t)_s * H + hd]; v##S = h2[(size_t)_s * 64 + lane]; }
#define PROCE(S, J)                                                        \
        if ((J) < end) {                                                   \
            float e = e##S + ad;                                           \
            e = e > 0.f ? e : NEG_SLOPE * e;                               \
            float mn = fmaxf(m, e);                                        \
            float corr = __expf(m - mn);                                   \
            float w = __expf(e - mn);                                      \
            m = mn;                                                        \
            z  = fmaf(z,  corr, w);                                        \
            a0 = fmaf(a0, corr, w * v##S.x);                               \
            a1 = fmaf(a1, corr, w * v##S.y);                               \
        }
        float e0, e1, e2, e3, e4, e5, e6, e7;
        float2 v0, v1, v2, v3, v4, v5, v6, v7;
        LOADE(0, beg)     LOADE(1, beg + 1) LOADE(2, beg + 2) LOADE(3, beg + 3)
        LOADE(4, beg + 4) LOADE(5, beg + 5) LOADE(6, beg + 6) LOADE(7, beg + 7)
        for (int j = beg; j < end; j += 8) {
            PROCE(0, j)     LOADE(0, j + 8)
            PROCE(1, j + 1) LOADE(1, j + 9)
            PROCE(2, j + 2) LOADE(2, j + 10)
            PROCE(3, j + 3) LOADE(3, j + 11)
            PROCE(4, j + 4) LOADE(4, j + 12)
            PROCE(5, j + 5) LOADE(5, j + 13)
            PROCE(6, j + 6) LOADE(6, j + 14)
            PROCE(7, j + 7) LOADE(7, j + 15)
        }
#undef LOADE
#undef PROCE
    }
    float inv = 1.f / (z + 1e-16f);
    int c2 = lane * 2;
    float r0 = fmaxf(a0 * inv + bias[c2], 0.f);
    float r1 = fmaxf(a1 * inv + bias[c2 + 1], 0.f);
    *(float2*)(out + (size_t)dst * HC + c2) = make_float2(r0, r1);
}

// ---------------- global mean pool: one block (128 threads) per graph ----------------
__global__ void pool_kernel(const float* __restrict__ x, const int* __restrict__ gptr,
                            float* __restrict__ pooled, int G) {
    int g = blockIdx.x;
    int c = threadIdx.x;
    int beg = gptr[g], end = gptr[g + 1];
    float acc = 0.f;
    for (int n = beg; n < end; ++n) acc += x[(size_t)n * HC + c];
    pooled[(size_t)g * HC + c] = acc / fmaxf((float)(end - beg), 1.f);
}

// ---------------- final MLP: [G,128] -> relu(128->10) -> 10->1 ----------------
__global__ void mlp_kernel(const float* __restrict__ pooled,
                           const float* __restrict__ fc1w, const float* __restrict__ fc1b,
                           const float* __restrict__ fc2w, const float* __restrict__ fc2b,
                           float* __restrict__ out, int G) {
    int g = blockIdx.x * 64 + threadIdx.x;
    if (g >= G) return;
    float hdn[10];
#pragma unroll
    for (int j = 0; j < 10; ++j) hdn[j] = fc1b[j];
    for (int k = 0; k < HC; ++k) {
        float v = pooled[(size_t)g * HC + k];
#pragma unroll
        for (int j = 0; j < 10; ++j) hdn[j] = fmaf(v, fc1w[k * 10 + j], hdn[j]);
    }
    float acc = fc2b[0];
#pragma unroll
    for (int j = 0; j < 10; ++j) acc = fmaf(fmaxf(hdn[j], 0.f), fc2w[j], acc);
    out[g] = acc;
}

extern "C" void kernel_launch(void* const* d_in, const int* in_sizes, int n_in,
                              void* d_out, int out_size, void* d_ws, size_t ws_size,
                              hipStream_t stream) {
    const int N = in_sizes[0] / 64;   // 50000
    const int E = in_sizes[1] / 2;    // 600000
    const int G = out_size;           // 500
    const int ET = E + N;

    const float* x     = (const float*)d_in[0];
    const int*   ei    = (const int*)d_in[1];
    const int*   batch = (const int*)d_in[2];
    const float* W1 = (const float*)d_in[3];
    const float* as1 = (const float*)d_in[4];
    const float* ad1 = (const float*)d_in[5];
    const float* b1 = (const float*)d_in[6];
    const float* W2 = (const float*)d_in[7];
    const float* as2 = (const float*)d_in[8];
    const float* ad2 = (const float*)d_in[9];
    const float* b2 = (const float*)d_in[10];
    const float* W3 = (const float*)d_in[11];
    const float* as3 = (const float*)d_in[12];
    const float* ad3 = (const float*)d_in[13];
    const float* b3 = (const float*)d_in[14];
    const float* fc1w = (const float*)d_in[15];
    const float* fc1b = (const float*)d_in[16];
    const float* fc2w = (const float*)d_in[17];
    const float* fc2b = (const float*)d_in[18];

    // -------- workspace layout --------
    float* ws = (float*)d_ws;
    float* h      = ws;                          // N*128
    float* xb0    = h + (size_t)N * HC;          // N*128
    float* xb1    = xb0 + (size_t)N * HC;        // N*128
    float* asrc   = xb1 + (size_t)N * HC;        // N*8
    float* adst   = asrc + (size_t)N * H;        // N*8
    float* pooled = adst + (size_t)N * H;        // G*128
    int* ints   = (int*)(pooled + (size_t)G * HC);
    int* deg    = ints;                          // N
    int* cursor = deg + N;                       // N
    int* gcnt   = cursor + N;                    // G
    int* rowptr = gcnt + G;                      // N+1
    int* gptr   = rowptr + N + 1;                // G+1
    int* partN  = gptr + G + 1;                  // 256
    int* partG  = partN + 256;                   // 256
    int* csr    = partG + 256;                   // ET

    dim3 blk(256);
    int grid_e = (ET + 255) / 256;
    int grid_n = (N + 255) / 256;
    int grid_agg = (N * 64 + 255) / 256;
    int nbN = (N + 1023) / 1024;
    int nbG = (G + 1023) / 1024;

    // -------- one-time CSR build (graph shared by all 3 layers) --------
    zero_int_kernel<<<(2 * N + G + 255) / 256, blk, 0, stream>>>(deg, 2 * N + G);
    hist_kernel<<<grid_e, blk, 0, stream>>>(ei, deg, E, N);
    batch_hist_kernel<<<grid_n, blk, 0, stream>>>(batch, gcnt, N);
    // rowptr = exclusive_scan(deg)
    scan_blk_kernel<<<nbN, blk, 0, stream>>>(deg, rowptr, partN, N);
    scan_part_kernel<<<1, blk, 0, stream>>>(partN, rowptr + N, nbN);
    scan_add_kernel<<<nbN, blk, 0, stream>>>(rowptr, partN, N);
    // gptr = exclusive_scan(gcnt)
    scan_blk_kernel<<<nbG, blk, 0, stream>>>(gcnt, gptr, partG, G);
    scan_part_kernel<<<1, blk, 0, stream>>>(partG, gptr + G, nbG);
    scan_add_kernel<<<nbG, blk, 0, stream>>>(gptr, partG, G);

    scatter_kernel<<<grid_e, blk, 0, stream>>>(ei, rowptr, cursor, csr, E, N);

    auto run_layer = [&](const float* xin, int K, const float* W, const float* as_,
                         const float* ad_, const float* b, float* out) {
        if (K == 64)
            gemm_kernel<64><<<(N + 31) / 32, blk, 0, stream>>>(xin, W, h, N);
        else
            gemm_kernel<128><<<(N + 31) / 32, blk, 0, stream>>>(xin, W, h, N);
        att_kernel<<<(N * H + 255) / 256, blk, 0, stream>>>(h, as_, ad_, asrc, adst, N);
        gat_agg_kernel<<<grid_agg, blk, 0, stream>>>(rowptr, csr, h, asrc, adst, b, out, N);
    };

    run_layer(x,   64,  W1, as1, ad1, b1, xb0);
    run_layer(xb0, 128, W2, as2, ad2, b2, xb1);
    run_layer(xb1, 128, W3, as3, ad3, b3, xb0);

    pool_kernel<<<G, dim3(128), 0, stream>>>(xb0, gptr, pooled, G);
    mlp_kernel<<<(G + 63) / 64, dim3(64), 0, stream>>>(pooled, fc1w, fc1b, fc2w, fc2b,
                                                       (float*)d_out, G);
}

// Round 7
// 400.204 us; speedup vs baseline: 6.4624x; 1.2077x over previous
//
#include <hip/hip_runtime.h>
#include <hip/hip_bf16.h>

#define H 8
#define C 16
#define HC 128
#define NEG_SLOPE 0.2f

// ---------------- init: zero counters + fill csr with sentinel ----------------
__global__ void init_build_kernel(int* __restrict__ zp, int nz,
                                  int* __restrict__ csr, int cap, int sentinel) {
    int i = blockIdx.x * 256 + threadIdx.x;
    if (i < nz) zp[i] = 0;
    if (i < cap) csr[i] = sentinel;
}

// ---------------- fused histograms: dst-degree + batch count ----------------
__global__ void hist_both_kernel(const int* __restrict__ ei, const int* __restrict__ batch,
                                 int* __restrict__ deg, int* __restrict__ gcnt, int E, int N) {
    int i = blockIdx.x * 256 + threadIdx.x;
    if (i < E + N) {
        int d = (i < E) ? ei[E + i] : i - E;
        atomicAdd(&deg[d], 1);
    }
    if (i < N) atomicAdd(&gcnt[batch[i]], 1);
}

// ======== 3-phase coalesced exclusive scan over TWO arrays in one pass ========
// pad8: round each input up to a multiple of 8 (used for CSR row padding)
__global__ void scan_blk2_kernel(const int* __restrict__ a1, int* __restrict__ o1,
                                 int* __restrict__ p1, int n1, int nb1, int pad1,
                                 const int* __restrict__ a2, int* __restrict__ o2,
                                 int* __restrict__ p2, int n2, int pad2) {
    __shared__ int sh[256];
    const int* a; int* o; int* p; int n, blk, pad;
    if ((int)blockIdx.x < nb1) { a = a1; o = o1; p = p1; n = n1; blk = blockIdx.x; pad = pad1; }
    else { a = a2; o = o2; p = p2; n = n2; blk = blockIdx.x - nb1; pad = pad2; }
    int tid = threadIdx.x;
    int base = blk * 1024 + tid * 4;
    int4 v = make_int4(0, 0, 0, 0);
    if (base + 3 < n) v = *(const int4*)(a + base);
    else {
        if (base < n)     v.x = a[base];
        if (base + 1 < n) v.y = a[base + 1];
        if (base + 2 < n) v.z = a[base + 2];
        if (base + 3 < n) v.w = a[base + 3];
    }
    if (pad) { v.x = (v.x + 7) & ~7; v.y = (v.y + 7) & ~7; v.z = (v.z + 7) & ~7; v.w = (v.w + 7) & ~7; }
    int s = v.x + v.y + v.z + v.w;
    sh[tid] = s;
    __syncthreads();
    for (int off = 1; off < 256; off <<= 1) {
        int t = (tid >= off) ? sh[tid - off] : 0;
        __syncthreads();
        sh[tid] += t;
        __syncthreads();
    }
    int excl = sh[tid] - s;
    int4 ov;
    ov.x = excl; ov.y = ov.x + v.x; ov.z = ov.y + v.y; ov.w = ov.z + v.z;
    if (base + 3 < n) *(int4*)(o + base) = ov;
    else {
        if (base < n)     o[base] = ov.x;
        if (base + 1 < n) o[base + 1] = ov.y;
        if (base + 2 < n) o[base + 2] = ov.z;
        if (base + 3 < n) o[base + 3] = ov.w;
    }
    if (tid == 255) p[blk] = sh[255];
}

__global__ void scan_part2_kernel(int* __restrict__ p1, int* __restrict__ tot1, int nb1,
                                  int* __restrict__ p2, int* __restrict__ tot2, int nb2) {
    __shared__ int sh[256];
    int tid = threadIdx.x;
    // array 1
    int v = (tid < nb1) ? p1[tid] : 0;
    sh[tid] = v;
    __syncthreads();
    for (int off = 1; off < 256; off <<= 1) {
        int t = (tid >= off) ? sh[tid - off] : 0;
        __syncthreads();
        sh[tid] += t;
        __syncthreads();
    }
    if (tid < nb1) p1[tid] = sh[tid] - v;
    if (tid == 255) *tot1 = sh[255];
    __syncthreads();
    // array 2
    v = (tid < nb2) ? p2[tid] : 0;
    sh[tid] = v;
    __syncthreads();
    for (int off = 1; off < 256; off <<= 1) {
        int t = (tid >= off) ? sh[tid - off] : 0;
        __syncthreads();
        sh[tid] += t;
        __syncthreads();
    }
    if (tid < nb2) p2[tid] = sh[tid] - v;
    if (tid == 255) *tot2 = sh[255];
}

__global__ void scan_add2_kernel(int* __restrict__ o1, const int* __restrict__ p1,
                                 int n1, int nb1,
                                 int* __restrict__ o2, const int* __restrict__ p2, int n2) {
    int* o; const int* p; int n, blk;
    if ((int)blockIdx.x < nb1) { o = o1; p = p1; n = n1; blk = blockIdx.x; }
    else { o = o2; p = p2; n = n2; blk = blockIdx.x - nb1; }
    int off = p[blk];
    int base = blk * 1024 + threadIdx.x * 4;
    if (base + 3 < n) {
        int4 v = *(const int4*)(o + base);
        v.x += off; v.y += off; v.z += off; v.w += off;
        *(int4*)(o + base) = v;
    } else {
        if (base < n)     o[base] += off;
        if (base + 1 < n) o[base + 1] += off;
        if (base + 2 < n) o[base + 2] += off;
        if (base + 3 < n) o[base + 3] += off;
    }
}

// ---------------- scatter edges into padded CSR (by destination) ----------------
__global__ void scatter_kernel(const int* __restrict__ ei, const int* __restrict__ rowptr,
                               int* __restrict__ cursor, int* __restrict__ csr_src,
                               int E, int N) {
    int i = blockIdx.x * 256 + threadIdx.x;
    if (i >= E + N) return;
    int s, d;
    if (i < E) { s = ei[i]; d = ei[E + i]; }
    else       { s = d = i - E; }
    int pos = atomicAdd(&cursor[d], 1);
    csr_src[rowptr[d] + pos] = s;
}

// ---------------- fused GEMM + attention coefficients ----------------
// h[n,128] = x[n,K] @ W[K,128]; then block-local asrc/adst dots from LDS tile.
// Block 0 additionally writes the sentinel row (h[n]=0, asrc[n]=-inf).
template <int K>
__global__ void gemm_att_kernel(const float* __restrict__ x, const float* __restrict__ W,
                                const float* __restrict__ as_, const float* __restrict__ ad_,
                                float* __restrict__ h, float* __restrict__ asrc,
                                float* __restrict__ adst, int n) {
    __shared__ float xs[32][HC];
    int tx = threadIdx.x & 31;
    int ty = threadIdx.x >> 5;
    int row0 = blockIdx.x * 32;

    if (blockIdx.x == 0) {
        if (threadIdx.x < HC) h[(size_t)n * HC + threadIdx.x] = 0.f;
        if (threadIdx.x < H)  asrc[(size_t)n * H + threadIdx.x] = -INFINITY;
    }

    const int NV = 32 * K / 4;
    for (int idx = threadIdx.x; idx < NV; idx += 256) {
        int rr = idx / (K / 4), kk = idx % (K / 4);
        int gr = row0 + rr;
        float4 v = (gr < n) ? ((const float4*)(x + (size_t)gr * K))[kk]
                            : make_float4(0.f, 0.f, 0.f, 0.f);
        *(float4*)(&xs[rr][kk * 4]) = v;
    }
    __syncthreads();

    const float* Wc = W + tx * 4;
    float acc[4][4];
#pragma unroll
    for (int r = 0; r < 4; ++r)
#pragma unroll
        for (int c = 0; c < 4; ++c) acc[r][c] = 0.f;

    for (int k = 0; k < K; k += 4) {
        float4 xr[4];
#pragma unroll
        for (int r = 0; r < 4; ++r)
            xr[r] = *(const float4*)(&xs[ty * 4 + r][k]);
        float4 wv[4];
#pragma unroll
        for (int kk = 0; kk < 4; ++kk)
            wv[kk] = *(const float4*)(Wc + (size_t)(k + kk) * HC);
#pragma unroll
        for (int r = 0; r < 4; ++r) {
            acc[r][0] = fmaf(xr[r].x, wv[0].x, acc[r][0]);
            acc[r][1] = fmaf(xr[r].x, wv[0].y, acc[r][1]);
            acc[r][2] = fmaf(xr[r].x, wv[0].z, acc[r][2]);
            acc[r][3] = fmaf(xr[r].x, wv[0].w, acc[r][3]);
            acc[r][0] = fmaf(xr[r].y, wv[1].x, acc[r][0]);
            acc[r][1] = fmaf(xr[r].y, wv[1].y, acc[r][1]);
            acc[r][2] = fmaf(xr[r].y, wv[1].z, acc[r][2]);
            acc[r][3] = fmaf(xr[r].y, wv[1].w, acc[r][3]);
            acc[r][0] = fmaf(xr[r].z, wv[2].x, acc[r][0]);
            acc[r][1] = fmaf(xr[r].z, wv[2].y, acc[r][1]);
            acc[r][2] = fmaf(xr[r].z, wv[2].z, acc[r][2]);
            acc[r][3] = fmaf(xr[r].z, wv[2].w, acc[r][3]);
            acc[r][0] = fmaf(xr[r].w, wv[3].x, acc[r][0]);
            acc[r][1] = fmaf(xr[r].w, wv[3].y, acc[r][1]);
            acc[r][2] = fmaf(xr[r].w, wv[3].z, acc[r][2]);
            acc[r][3] = fmaf(xr[r].w, wv[3].w, acc[r][3]);
        }
    }
    __syncthreads();  // all xs reads done before overwrite
#pragma unroll
    for (int r = 0; r < 4; ++r) {
        float4 o = make_float4(acc[r][0], acc[r][1], acc[r][2], acc[r][3]);
        *(float4*)(&xs[ty * 4 + r][tx * 4]) = o;
        int row = row0 + ty * 4 + r;
        if (row < n) *(float4*)(h + (size_t)row * HC + tx * 4) = o;
    }
    __syncthreads();

    // attention dots: thread = (row, head)
    int row = threadIdx.x >> 3;
    int hd = threadIdx.x & 7;
    if (row0 + row < n) {
        const float4* hv = (const float4*)&xs[row][hd * 16];
        const float4* sv = (const float4*)(as_ + hd * 16);
        const float4* dv = (const float4*)(ad_ + hd * 16);
        float s = 0.f, d = 0.f;
#pragma unroll
        for (int j = 0; j < 4; ++j) {
            float4 a = hv[j], u = sv[j], v = dv[j];
            s += a.x * u.x + a.y * u.y + a.z * u.z + a.w * u.w;
            d += a.x * v.x + a.y * v.y + a.z * v.z + a.w * v.w;
        }
        asrc[(size_t)(row0 + row) * H + hd] = s;
        adst[(size_t)(row0 + row) * H + hd] = d;
    }
}

// ---------------- fused GAT aggregation: one wave per destination ----------------
// Sentinel-padded rows (multiple of 8, sentinel src=N -> w=0), straight-line body,
// 3-stage pipeline: idx prefetched 2 groups ahead, values 1 group ahead.
__global__ void gat_agg_kernel(const int* __restrict__ rowptr, const int* __restrict__ csr_src,
                               const float* __restrict__ h, const float* __restrict__ asrc,
                               const float* __restrict__ adst, const float* __restrict__ bias,
                               float* __restrict__ out, int N) {
    int dst = (blockIdx.x * 256 + threadIdx.x) >> 6;  // one wave per dst
    if (dst >= N) return;
    int lane = threadIdx.x & 63;
    int hd = lane >> 3;
    int beg = rowptr[dst], end = rowptr[dst + 1];
    float ad = adst[(size_t)dst * H + hd];
    const float2* h2 = (const float2*)h;  // row stride = 64 float2

    float m = -INFINITY, z = 0.f, a0 = 0.f, a1 = 0.f;
    int i0, i1, i2, i3, i4, i5, i6, i7;
    float e0, e1, e2, e3, e4, e5, e6, e7;
    float2 v0, v1, v2, v3, v4, v5, v6, v7;

#define LOADI(S, J) i##S = csr_src[(J)];
#define LOADV(S)                                                           \
    { e##S = asrc[(size_t)i##S * H + hd]; v##S = h2[(size_t)i##S * 64 + lane]; }
#define PROCE(S)                                                           \
    {   float e = e##S + ad;                                               \
        e = e > 0.f ? e : NEG_SLOPE * e;                                   \
        float mn = fmaxf(m, e);                                            \
        float corr = __expf(m - mn);                                       \
        float w = __expf(e - mn);                                          \
        m = mn;                                                            \
        z  = fmaf(z,  corr, w);                                            \
        a0 = fmaf(a0, corr, w * v##S.x);                                   \
        a1 = fmaf(a1, corr, w * v##S.y);                                   \
    }
    // prologue: idx g0, vals g0, idx g1
    LOADI(0, beg)     LOADI(1, beg + 1) LOADI(2, beg + 2) LOADI(3, beg + 3)
    LOADI(4, beg + 4) LOADI(5, beg + 5) LOADI(6, beg + 6) LOADI(7, beg + 7)
    LOADV(0) LOADV(1) LOADV(2) LOADV(3) LOADV(4) LOADV(5) LOADV(6) LOADV(7)
    LOADI(0, beg + 8)  LOADI(1, beg + 9)  LOADI(2, beg + 10) LOADI(3, beg + 11)
    LOADI(4, beg + 12) LOADI(5, beg + 13) LOADI(6, beg + 14) LOADI(7, beg + 15)

    for (int j = beg; j < end; j += 8) {
        PROCE(0) LOADV(0)
        PROCE(1) LOADV(1)
        PROCE(2) LOADV(2)
        PROCE(3) LOADV(3)
        PROCE(4) LOADV(4)
        PROCE(5) LOADV(5)
        PROCE(6) LOADV(6)
        PROCE(7) LOADV(7)
        LOADI(0, j + 16) LOADI(1, j + 17) LOADI(2, j + 18) LOADI(3, j + 19)
        LOADI(4, j + 20) LOADI(5, j + 21) LOADI(6, j + 22) LOADI(7, j + 23)
    }
#undef LOADI
#undef LOADV
#undef PROCE
    float inv = 1.f / (z + 1e-16f);
    int c2 = lane * 2;
    float r0 = fmaxf(a0 * inv + bias[c2], 0.f);
    float r1 = fmaxf(a1 * inv + bias[c2 + 1], 0.f);
    *(float2*)(out + (size_t)dst * HC + c2) = make_float2(r0, r1);
}

// ---------------- fused global mean pool + MLP: one block (128 threads) per graph ---
__global__ void pool_mlp_kernel(const float* __restrict__ x, const int* __restrict__ gptr,
                                const float* __restrict__ fc1w, const float* __restrict__ fc1b,
                                const float* __restrict__ fc2w, const float* __restrict__ fc2b,
                                float* __restrict__ out, int G) {
    __shared__ float sp[HC];
    __shared__ float sh[10];
    int g = blockIdx.x;
    int c = threadIdx.x;  // 0..127
    int beg = gptr[g], end = gptr[g + 1];
    float acc = 0.f;
    for (int n = beg; n < end; ++n) acc += x[(size_t)n * HC + c];
    sp[c] = acc / fmaxf((float)(end - beg), 1.f);
    __syncthreads();
    if (c < 10) {
        float s = fc1b[c];
        for (int k = 0; k < HC; ++k) s = fmaf(sp[k], fc1w[k * 10 + c], s);
        sh[c] = fmaxf(s, 0.f);
    }
    __syncthreads();
    if (c == 0) {
        float o = fc2b[0];
#pragma unroll
        for (int j = 0; j < 10; ++j) o = fmaf(sh[j], fc2w[j], o);
        out[g] = o;
    }
}

extern "C" void kernel_launch(void* const* d_in, const int* in_sizes, int n_in,
                              void* d_out, int out_size, void* d_ws, size_t ws_size,
                              hipStream_t stream) {
    const int N = in_sizes[0] / 64;   // 50000
    const int E = in_sizes[1] / 2;    // 600000
    const int G = out_size;           // 500
    const int ET = E + N;
    const int CSR_CAP = E + 8 * N + 64;  // padded-row worst case + prefetch margin

    const float* x     = (const float*)d_in[0];
    const int*   ei    = (const int*)d_in[1];
    const int*   batch = (const int*)d_in[2];
    const float* W1 = (const float*)d_in[3];
    const float* as1 = (const float*)d_in[4];
    const float* ad1 = (const float*)d_in[5];
    const float* b1 = (const float*)d_in[6];
    const float* W2 = (const float*)d_in[7];
    const float* as2 = (const float*)d_in[8];
    const float* ad2 = (const float*)d_in[9];
    const float* b2 = (const float*)d_in[10];
    const float* W3 = (const float*)d_in[11];
    const float* as3 = (const float*)d_in[12];
    const float* ad3 = (const float*)d_in[13];
    const float* b3 = (const float*)d_in[14];
    const float* fc1w = (const float*)d_in[15];
    const float* fc1b = (const float*)d_in[16];
    const float* fc2w = (const float*)d_in[17];
    const float* fc2b = (const float*)d_in[18];

    // -------- workspace layout (16B alignment maintained between regions) --------
    float* ws = (float*)d_ws;
    float* h    = ws;                            // (N+1)*128
    float* xb0  = h + (size_t)(N + 1) * HC;      // N*128
    float* xb1  = xb0 + (size_t)N * HC;          // N*128
    float* asrc = xb1 + (size_t)N * HC;          // (N+1)*8
    float* adst = asrc + (size_t)(N + 1) * H;    // N*8
    int* ints   = (int*)(adst + (size_t)N * H);
    int* deg    = ints;                          // N
    int* cursor = deg + N;                       // N
    int* gcnt   = cursor + N;                    // G (500, 16B-mult)
    int* rowptr = gcnt + G;                      // N+1 (alloc N+16)
    int* gptr   = rowptr + N + 16;               // G+1 (alloc G+16)
    int* partN  = gptr + G + 16;                 // 256
    int* partG  = partN + 256;                   // 256
    int* csr    = partG + 256;                   // CSR_CAP

    dim3 blk(256);
    int grid_e   = (ET + 255) / 256;
    int grid_agg = (N * 64 + 255) / 256;
    int nbN = (N + 1023) / 1024;
    int nbG = (G + 1023) / 1024;
    int nz = 2 * N + G;
    int grid_init = (max(nz, CSR_CAP) + 255) / 256;

    // -------- one-time CSR build (graph shared by all 3 layers) --------
    init_build_kernel<<<grid_init, blk, 0, stream>>>(deg, nz, csr, CSR_CAP, N);
    hist_both_kernel<<<grid_e, blk, 0, stream>>>(ei, batch, deg, gcnt, E, N);
    scan_blk2_kernel<<<nbN + nbG, blk, 0, stream>>>(deg, rowptr, partN, N, nbN, 1,
                                                    gcnt, gptr, partG, G, 0);
    scan_part2_kernel<<<1, blk, 0, stream>>>(partN, rowptr + N, nbN, partG, gptr + G, nbG);
    scan_add2_kernel<<<nbN + nbG, blk, 0, stream>>>(rowptr, partN, N, nbN, gptr, partG, G);
    scatter_kernel<<<grid_e, blk, 0, stream>>>(ei, rowptr, cursor, csr, E, N);

    auto run_layer = [&](const float* xin, int K, const float* W, const float* as_,
                         const float* ad_, const float* b, float* out) {
        if (K == 64)
            gemm_att_kernel<64><<<(N + 31) / 32, blk, 0, stream>>>(xin, W, as_, ad_,
                                                                   h, asrc, adst, N);
        else
            gemm_att_kernel<128><<<(N + 31) / 32, blk, 0, stream>>>(xin, W, as_, ad_,
                                                                    h, asrc, adst, N);
        gat_agg_kernel<<<grid_agg, blk, 0, stream>>>(rowptr, csr, h, asrc, adst, b, out, N);
    };

    run_layer(x,   64,  W1, as1, ad1, b1, xb0);
    run_layer(xb0, 128, W2, as2, ad2, b2, xb1);
    run_layer(xb1, 128, W3, as3, ad3, b3, xb0);

    pool_mlp_kernel<<<G, dim3(128), 0, stream>>>(xb0, gptr, fc1w, fc1b, fc2w, fc2b,
                                                 (float*)d_out, G);
}

// Round 8
// 393.282 us; speedup vs baseline: 6.5761x; 1.0176x over previous
//
#include <hip/hip_runtime.h>
#include <hip/hip_bf16.h>

#define H 8
#define C 16
#define HC 128
#define NEG_SLOPE 0.2f

// ---------------- init: zero counters + fill csr with sentinel ----------------
__global__ void init_build_kernel(int* __restrict__ zp, int nz,
                                  int* __restrict__ csr, int cap, int sentinel) {
    int i = blockIdx.x * 256 + threadIdx.x;
    if (i < nz) zp[i] = 0;
    if (i < cap) csr[i] = sentinel;
}

// ---------------- fused histograms: dst-degree + batch count ----------------
__global__ void hist_both_kernel(const int* __restrict__ ei, const int* __restrict__ batch,
                                 int* __restrict__ deg, int* __restrict__ gcnt, int E, int N) {
    int i = blockIdx.x * 256 + threadIdx.x;
    if (i < E + N) {
        int d = (i < E) ? ei[E + i] : i - E;
        atomicAdd(&deg[d], 1);
    }
    if (i < N) atomicAdd(&gcnt[batch[i]], 1);
}

// ======== 3-phase coalesced exclusive scan over TWO arrays in one pass ========
__global__ void scan_blk2_kernel(const int* __restrict__ a1, int* __restrict__ o1,
                                 int* __restrict__ p1, int n1, int nb1, int pad1,
                                 const int* __restrict__ a2, int* __restrict__ o2,
                                 int* __restrict__ p2, int n2, int pad2) {
    __shared__ int sh[256];
    const int* a; int* o; int* p; int n, blk, pad;
    if ((int)blockIdx.x < nb1) { a = a1; o = o1; p = p1; n = n1; blk = blockIdx.x; pad = pad1; }
    else { a = a2; o = o2; p = p2; n = n2; blk = blockIdx.x - nb1; pad = pad2; }
    int tid = threadIdx.x;
    int base = blk * 1024 + tid * 4;
    int4 v = make_int4(0, 0, 0, 0);
    if (base + 3 < n) v = *(const int4*)(a + base);
    else {
        if (base < n)     v.x = a[base];
        if (base + 1 < n) v.y = a[base + 1];
        if (base + 2 < n) v.z = a[base + 2];
        if (base + 3 < n) v.w = a[base + 3];
    }
    if (pad) { v.x = (v.x + 7) & ~7; v.y = (v.y + 7) & ~7; v.z = (v.z + 7) & ~7; v.w = (v.w + 7) & ~7; }
    int s = v.x + v.y + v.z + v.w;
    sh[tid] = s;
    __syncthreads();
    for (int off = 1; off < 256; off <<= 1) {
        int t = (tid >= off) ? sh[tid - off] : 0;
        __syncthreads();
        sh[tid] += t;
        __syncthreads();
    }
    int excl = sh[tid] - s;
    int4 ov;
    ov.x = excl; ov.y = ov.x + v.x; ov.z = ov.y + v.y; ov.w = ov.z + v.z;
    if (base + 3 < n) *(int4*)(o + base) = ov;
    else {
        if (base < n)     o[base] = ov.x;
        if (base + 1 < n) o[base + 1] = ov.y;
        if (base + 2 < n) o[base + 2] = ov.z;
        if (base + 3 < n) o[base + 3] = ov.w;
    }
    if (tid == 255) p[blk] = sh[255];
}

__global__ void scan_part2_kernel(int* __restrict__ p1, int* __restrict__ tot1, int nb1,
                                  int* __restrict__ p2, int* __restrict__ tot2, int nb2) {
    __shared__ int sh[256];
    int tid = threadIdx.x;
    int v = (tid < nb1) ? p1[tid] : 0;
    sh[tid] = v;
    __syncthreads();
    for (int off = 1; off < 256; off <<= 1) {
        int t = (tid >= off) ? sh[tid - off] : 0;
        __syncthreads();
        sh[tid] += t;
        __syncthreads();
    }
    if (tid < nb1) p1[tid] = sh[tid] - v;
    if (tid == 255) *tot1 = sh[255];
    __syncthreads();
    v = (tid < nb2) ? p2[tid] : 0;
    sh[tid] = v;
    __syncthreads();
    for (int off = 1; off < 256; off <<= 1) {
        int t = (tid >= off) ? sh[tid - off] : 0;
        __syncthreads();
        sh[tid] += t;
        __syncthreads();
    }
    if (tid < nb2) p2[tid] = sh[tid] - v;
    if (tid == 255) *tot2 = sh[255];
}

__global__ void scan_add2_kernel(int* __restrict__ o1, const int* __restrict__ p1,
                                 int n1, int nb1,
                                 int* __restrict__ o2, const int* __restrict__ p2, int n2) {
    int* o; const int* p; int n, blk;
    if ((int)blockIdx.x < nb1) { o = o1; p = p1; n = n1; blk = blockIdx.x; }
    else { o = o2; p = p2; n = n2; blk = blockIdx.x - nb1; }
    int off = p[blk];
    int base = blk * 1024 + threadIdx.x * 4;
    if (base + 3 < n) {
        int4 v = *(const int4*)(o + base);
        v.x += off; v.y += off; v.z += off; v.w += off;
        *(int4*)(o + base) = v;
    } else {
        if (base < n)     o[base] += off;
        if (base + 1 < n) o[base + 1] += off;
        if (base + 2 < n) o[base + 2] += off;
        if (base + 3 < n) o[base + 3] += off;
    }
}

// ---------------- scatter edges into padded CSR (by destination) ----------------
__global__ void scatter_kernel(const int* __restrict__ ei, const int* __restrict__ rowptr,
                               int* __restrict__ cursor, int* __restrict__ csr_src,
                               int E, int N) {
    int i = blockIdx.x * 256 + threadIdx.x;
    if (i >= E + N) return;
    int s, d;
    if (i < E) { s = ei[i]; d = ei[E + i]; }
    else       { s = d = i - E; }
    int pos = atomicAdd(&cursor[d], 1);
    csr_src[rowptr[d] + pos] = s;
}

// ---------------- fused GEMM + attention coefficients ----------------
// 64x128 tile, 256 threads, each thread 8 rows x 4 cols.
// Block 0 additionally writes the sentinel row (h[n]=0, asrc[n]=-inf).
template <int K>
__global__ void gemm_att_kernel(const float* __restrict__ x, const float* __restrict__ W,
                                const float* __restrict__ as_, const float* __restrict__ ad_,
                                float* __restrict__ h, float* __restrict__ asrc,
                                float* __restrict__ adst, int n) {
    const int ROWS = 64;
    __shared__ float xs[ROWS][HC];  // K cols used for staging, 128 for output
    int tx = threadIdx.x & 31;
    int ty = threadIdx.x >> 5;
    int row0 = blockIdx.x * ROWS;

    if (blockIdx.x == 0) {
        if (threadIdx.x < HC) h[(size_t)n * HC + threadIdx.x] = 0.f;
        if (threadIdx.x < H)  asrc[(size_t)n * H + threadIdx.x] = -INFINITY;
    }

    const int NV = ROWS * K / 4;
    for (int idx = threadIdx.x; idx < NV; idx += 256) {
        int rr = idx / (K / 4), kk = idx % (K / 4);
        int gr = row0 + rr;
        float4 v = (gr < n) ? ((const float4*)(x + (size_t)gr * K))[kk]
                            : make_float4(0.f, 0.f, 0.f, 0.f);
        *(float4*)(&xs[rr][kk * 4]) = v;
    }
    __syncthreads();

    const float* Wc = W + tx * 4;
    float acc[8][4];
#pragma unroll
    for (int r = 0; r < 8; ++r)
#pragma unroll
        for (int c = 0; c < 4; ++c) acc[r][c] = 0.f;

    for (int k = 0; k < K; k += 4) {
        float4 wv[4];
#pragma unroll
        for (int kk = 0; kk < 4; ++kk)
            wv[kk] = *(const float4*)(Wc + (size_t)(k + kk) * HC);
#pragma unroll
        for (int r = 0; r < 8; ++r) {
            float4 xr = *(const float4*)(&xs[ty * 8 + r][k]);
            acc[r][0] = fmaf(xr.x, wv[0].x, acc[r][0]);
            acc[r][1] = fmaf(xr.x, wv[0].y, acc[r][1]);
            acc[r][2] = fmaf(xr.x, wv[0].z, acc[r][2]);
            acc[r][3] = fmaf(xr.x, wv[0].w, acc[r][3]);
            acc[r][0] = fmaf(xr.y, wv[1].x, acc[r][0]);
            acc[r][1] = fmaf(xr.y, wv[1].y, acc[r][1]);
            acc[r][2] = fmaf(xr.y, wv[1].z, acc[r][2]);
            acc[r][3] = fmaf(xr.y, wv[1].w, acc[r][3]);
            acc[r][0] = fmaf(xr.z, wv[2].x, acc[r][0]);
            acc[r][1] = fmaf(xr.z, wv[2].y, acc[r][1]);
            acc[r][2] = fmaf(xr.z, wv[2].z, acc[r][2]);
            acc[r][3] = fmaf(xr.z, wv[2].w, acc[r][3]);
            acc[r][0] = fmaf(xr.w, wv[3].x, acc[r][0]);
            acc[r][1] = fmaf(xr.w, wv[3].y, acc[r][1]);
            acc[r][2] = fmaf(xr.w, wv[3].z, acc[r][2]);
            acc[r][3] = fmaf(xr.w, wv[3].w, acc[r][3]);
        }
    }
    __syncthreads();  // all xs reads done before overwrite
#pragma unroll
    for (int r = 0; r < 8; ++r) {
        float4 o = make_float4(acc[r][0], acc[r][1], acc[r][2], acc[r][3]);
        *(float4*)(&xs[ty * 8 + r][tx * 4]) = o;
        int row = row0 + ty * 8 + r;
        if (row < n) *(float4*)(h + (size_t)row * HC + tx * 4) = o;
    }
    __syncthreads();

    // attention dots: 512 (row,head) pairs, 2 per thread
#pragma unroll
    for (int rep = 0; rep < 2; ++rep) {
        int pidx = threadIdx.x + rep * 256;
        int row = pidx >> 3;
        int hd = pidx & 7;
        if (row0 + row < n) {
            const float4* hv = (const float4*)&xs[row][hd * 16];
            const float4* sv = (const float4*)(as_ + hd * 16);
            const float4* dv = (const float4*)(ad_ + hd * 16);
            float s = 0.f, d = 0.f;
#pragma unroll
            for (int j = 0; j < 4; ++j) {
                float4 a = hv[j], u = sv[j], v = dv[j];
                s += a.x * u.x + a.y * u.y + a.z * u.z + a.w * u.w;
                d += a.x * v.x + a.y * v.y + a.z * v.z + a.w * v.w;
            }
            asrc[(size_t)(row0 + row) * H + hd] = s;
            adst[(size_t)(row0 + row) * H + hd] = d;
        }
    }
}

// ---------------- fused GAT aggregation: one wave per destination ----------------
// No-max softmax (scores bounded; shift-invariance => identical alpha).
// Sentinel-padded rows (multiple of 8, sentinel src=N -> w=0), straight-line body,
// 3-stage pipeline: idx prefetched 2 groups ahead, values 1 group ahead.
__global__ void gat_agg_kernel(const int* __restrict__ rowptr, const int* __restrict__ csr_src,
                               const float* __restrict__ h, const float* __restrict__ asrc,
                               const float* __restrict__ adst, const float* __restrict__ bias,
                               float* __restrict__ out, int N) {
    int dst = (blockIdx.x * 256 + threadIdx.x) >> 6;  // one wave per dst
    if (dst >= N) return;
    int lane = threadIdx.x & 63;
    int hd = lane >> 3;
    int beg = rowptr[dst], end = rowptr[dst + 1];
    float ad = adst[(size_t)dst * H + hd];
    const float2* h2 = (const float2*)h;  // row stride = 64 float2

    float z = 0.f, a0 = 0.f, a1 = 0.f;
    int i0, i1, i2, i3, i4, i5, i6, i7;
    float e0, e1, e2, e3, e4, e5, e6, e7;
    float2 v0, v1, v2, v3, v4, v5, v6, v7;

#define LOADI(S, J) i##S = csr_src[(J)];
#define LOADV(S)                                                           \
    { e##S = asrc[(size_t)i##S * H + hd]; v##S = h2[(size_t)i##S * 64 + lane]; }
#define PROCE(S)                                                           \
    {   float e = e##S + ad;                                               \
        e = e > 0.f ? e : NEG_SLOPE * e;                                   \
        float w = __expf(e);                                               \
        z += w;                                                            \
        a0 = fmaf(w, v##S.x, a0);                                          \
        a1 = fmaf(w, v##S.y, a1);                                          \
    }
    // prologue: idx g0, vals g0, idx g1
    LOADI(0, beg)     LOADI(1, beg + 1) LOADI(2, beg + 2) LOADI(3, beg + 3)
    LOADI(4, beg + 4) LOADI(5, beg + 5) LOADI(6, beg + 6) LOADI(7, beg + 7)
    LOADV(0) LOADV(1) LOADV(2) LOADV(3) LOADV(4) LOADV(5) LOADV(6) LOADV(7)
    LOADI(0, beg + 8)  LOADI(1, beg + 9)  LOADI(2, beg + 10) LOADI(3, beg + 11)
    LOADI(4, beg + 12) LOADI(5, beg + 13) LOADI(6, beg + 14) LOADI(7, beg + 15)

    for (int j = beg; j < end; j += 8) {
        PROCE(0) LOADV(0)
        PROCE(1) LOADV(1)
        PROCE(2) LOADV(2)
        PROCE(3) LOADV(3)
        PROCE(4) LOADV(4)
        PROCE(5) LOADV(5)
        PROCE(6) LOADV(6)
        PROCE(7) LOADV(7)
        LOADI(0, j + 16) LOADI(1, j + 17) LOADI(2, j + 18) LOADI(3, j + 19)
        LOADI(4, j + 20) LOADI(5, j + 21) LOADI(6, j + 22) LOADI(7, j + 23)
    }
#undef LOADI
#undef LOADV
#undef PROCE
    float inv = 1.f / (z + 1e-16f);
    int c2 = lane * 2;
    float r0 = fmaxf(a0 * inv + bias[c2], 0.f);
    float r1 = fmaxf(a1 * inv + bias[c2 + 1], 0.f);
    *(float2*)(out + (size_t)dst * HC + c2) = make_float2(r0, r1);
}

// ---------------- fused global mean pool + MLP: one block (128 threads) per graph ---
__global__ void pool_mlp_kernel(const float* __restrict__ x, const int* __restrict__ gptr,
                                const float* __restrict__ fc1w, const float* __restrict__ fc1b,
                                const float* __restrict__ fc2w, const float* __restrict__ fc2b,
                                float* __restrict__ out, int G) {
    __shared__ float sp[HC];
    __shared__ float sh[10];
    int g = blockIdx.x;
    int c = threadIdx.x;  // 0..127
    int beg = gptr[g], end = gptr[g + 1];
    float acc = 0.f;
    for (int n = beg; n < end; ++n) acc += x[(size_t)n * HC + c];
    sp[c] = acc / fmaxf((float)(end - beg), 1.f);
    __syncthreads();
    if (c < 10) {
        float s = fc1b[c];
        for (int k = 0; k < HC; ++k) s = fmaf(sp[k], fc1w[k * 10 + c], s);
        sh[c] = fmaxf(s, 0.f);
    }
    __syncthreads();
    if (c == 0) {
        float o = fc2b[0];
#pragma unroll
        for (int j = 0; j < 10; ++j) o = fmaf(sh[j], fc2w[j], o);
        out[g] = o;
    }
}

extern "C" void kernel_launch(void* const* d_in, const int* in_sizes, int n_in,
                              void* d_out, int out_size, void* d_ws, size_t ws_size,
                              hipStream_t stream) {
    const int N = in_sizes[0] / 64;   // 50000
    const int E = in_sizes[1] / 2;    // 600000
    const int G = out_size;           // 500
    const int ET = E + N;
    const int CSR_CAP = E + 8 * N + 64;  // padded-row worst case + prefetch margin

    const float* x     = (const float*)d_in[0];
    const int*   ei    = (const int*)d_in[1];
    const int*   batch = (const int*)d_in[2];
    const float* W1 = (const float*)d_in[3];
    const float* as1 = (const float*)d_in[4];
    const float* ad1 = (const float*)d_in[5];
    const float* b1 = (const float*)d_in[6];
    const float* W2 = (const float*)d_in[7];
    const float* as2 = (const float*)d_in[8];
    const float* ad2 = (const float*)d_in[9];
    const float* b2 = (const float*)d_in[10];
    const float* W3 = (const float*)d_in[11];
    const float* as3 = (const float*)d_in[12];
    const float* ad3 = (const float*)d_in[13];
    const float* b3 = (const float*)d_in[14];
    const float* fc1w = (const float*)d_in[15];
    const float* fc1b = (const float*)d_in[16];
    const float* fc2w = (const float*)d_in[17];
    const float* fc2b = (const float*)d_in[18];

    // -------- workspace layout --------
    float* ws = (float*)d_ws;
    float* h    = ws;                            // (N+1)*128
    float* xb0  = h + (size_t)(N + 1) * HC;      // N*128
    float* xb1  = xb0 + (size_t)N * HC;          // N*128
    float* asrc = xb1 + (size_t)N * HC;          // (N+1)*8
    float* adst = asrc + (size_t)(N + 1) * H;    // N*8
    int* ints   = (int*)(adst + (size_t)N * H);
    int* deg    = ints;                          // N
    int* cursor = deg + N;                       // N
    int* gcnt   = cursor + N;                    // G
    int* rowptr = gcnt + G;                      // N+1 (alloc N+16)
    int* gptr   = rowptr + N + 16;               // G+1 (alloc G+16)
    int* partN  = gptr + G + 16;                 // 256
    int* partG  = partN + 256;                   // 256
    int* csr    = partG + 256;                   // CSR_CAP

    dim3 blk(256);
    int grid_e   = (ET + 255) / 256;
    int grid_agg = (N * 64 + 255) / 256;
    int nbN = (N + 1023) / 1024;
    int nbG = (G + 1023) / 1024;
    int nz = 2 * N + G;
    int grid_init = (max(nz, CSR_CAP) + 255) / 256;

    // -------- one-time CSR build (graph shared by all 3 layers) --------
    init_build_kernel<<<grid_init, blk, 0, stream>>>(deg, nz, csr, CSR_CAP, N);
    hist_both_kernel<<<grid_e, blk, 0, stream>>>(ei, batch, deg, gcnt, E, N);
    scan_blk2_kernel<<<nbN + nbG, blk, 0, stream>>>(deg, rowptr, partN, N, nbN, 1,
                                                    gcnt, gptr, partG, G, 0);
    scan_part2_kernel<<<1, blk, 0, stream>>>(partN, rowptr + N, nbN, partG, gptr + G, nbG);
    scan_add2_kernel<<<nbN + nbG, blk, 0, stream>>>(rowptr, partN, N, nbN, gptr, partG, G);
    scatter_kernel<<<grid_e, blk, 0, stream>>>(ei, rowptr, cursor, csr, E, N);

    auto run_layer = [&](const float* xin, int K, const float* W, const float* as_,
                         const float* ad_, const float* b, float* out) {
        if (K == 64)
            gemm_att_kernel<64><<<(N + 63) / 64, blk, 0, stream>>>(xin, W, as_, ad_,
                                                                   h, asrc, adst, N);
        else
            gemm_att_kernel<128><<<(N + 63) / 64, blk, 0, stream>>>(xin, W, as_, ad_,
                                                                    h, asrc, adst, N);
        gat_agg_kernel<<<grid_agg, blk, 0, stream>>>(rowptr, csr, h, asrc, adst, b, out, N);
    };

    run_layer(x,   64,  W1, as1, ad1, b1, xb0);
    run_layer(xb0, 128, W2, as2, ad2, b2, xb1);
    run_layer(xb1, 128, W3, as3, ad3, b3, xb0);

    pool_mlp_kernel<<<G, dim3(128), 0, stream>>>(xb0, gptr, fc1w, fc1b, fc2w, fc2b,
                                                 (float*)d_out, G);
}

// Round 9
// 365.996 us; speedup vs baseline: 7.0664x; 1.0746x over previous
//
#include <hip/hip_runtime.h>
#include <hip/hip_bf16.h>

#define H 8
#define C 16
#define HC 128
#define NEG_SLOPE 0.2f

// ---------------- init: zero the 8-way degree counters ----------------
__global__ void init_kernel(int* __restrict__ deg8, int n) {
    int i = blockIdx.x * 256 + threadIdx.x;
    if (i < n) deg8[i] = 0;
}

// ---------------- 8-way histogram (4 edges/thread) + gptr boundaries ----------------
__global__ void hist8_gptr_kernel(const int* __restrict__ ei, const int* __restrict__ batch,
                                  int* __restrict__ deg8, int* __restrict__ gptr,
                                  int E, int N, int G) {
    int t = blockIdx.x * 256 + threadIdx.x;
    int* dg = deg8 + (size_t)(blockIdx.x & 7) * N;
    int e0 = t * 4;
    if (e0 + 3 < E) {
        int4 d4 = *(const int4*)(ei + E + e0);
        atomicAdd(&dg[d4.x], 1);
        atomicAdd(&dg[d4.y], 1);
        atomicAdd(&dg[d4.z], 1);
        atomicAdd(&dg[d4.w], 1);
    } else if (e0 < E) {
        for (int j = e0; j < E; ++j) atomicAdd(&dg[ei[E + j]], 1);
    }
    int n0 = t * 4;
    if (n0 < N) {
        int v0 = batch[n0];
        int v1 = (n0 + 1 < N) ? batch[n0 + 1] : v0;
        int v2 = (n0 + 2 < N) ? batch[n0 + 2] : v1;
        int v3 = (n0 + 3 < N) ? batch[n0 + 3] : v2;
        int vals[4] = {v0, v1, v2, v3};
        int prev = (n0 == 0) ? -1 : batch[n0 - 1];
        for (int j = 0; j < 4; ++j) {
            int i = n0 + j;
            if (i >= N) break;
            int cur = vals[j];
            if (cur != prev)
                for (int g = prev + 1; g <= cur; ++g) gptr[g] = i;
            if (i == N - 1)
                for (int g = cur + 1; g <= G; ++g) gptr[g] = N;
            prev = cur;
        }
    }
}

// ---------------- reduce 8 copies -> deg (incl. self loop) ----------------
__global__ void deg_reduce_kernel(const int* __restrict__ deg8, int* __restrict__ deg, int N) {
    int d = blockIdx.x * 256 + threadIdx.x;
    if (d >= N) return;
    int s = 1;  // self loop
#pragma unroll
    for (int c = 0; c < 8; ++c) s += deg8[(size_t)c * N + d];
    deg[d] = s;
}

// ======== 3-phase coalesced exclusive scan (pad8 applied to inputs) ========
__global__ void scan_blk_kernel(const int* __restrict__ a, int* __restrict__ o,
                                int* __restrict__ p, int n) {
    __shared__ int sh[256];
    int tid = threadIdx.x;
    int base = blockIdx.x * 1024 + tid * 4;
    int4 v = make_int4(0, 0, 0, 0);
    if (base + 3 < n) v = *(const int4*)(a + base);
    else {
        if (base < n)     v.x = a[base];
        if (base + 1 < n) v.y = a[base + 1];
        if (base + 2 < n) v.z = a[base + 2];
        if (base + 3 < n) v.w = a[base + 3];
    }
    v.x = (v.x + 7) & ~7; v.y = (v.y + 7) & ~7; v.z = (v.z + 7) & ~7; v.w = (v.w + 7) & ~7;
    if (base >= n)     v.x = 0;
    if (base + 1 >= n) v.y = 0;
    if (base + 2 >= n) v.z = 0;
    if (base + 3 >= n) v.w = 0;
    int s = v.x + v.y + v.z + v.w;
    sh[tid] = s;
    __syncthreads();
    for (int off = 1; off < 256; off <<= 1) {
        int t = (tid >= off) ? sh[tid - off] : 0;
        __syncthreads();
        sh[tid] += t;
        __syncthreads();
    }
    int excl = sh[tid] - s;
    int4 ov;
    ov.x = excl; ov.y = ov.x + v.x; ov.z = ov.y + v.y; ov.w = ov.z + v.z;
    if (base + 3 < n) *(int4*)(o + base) = ov;
    else {
        if (base < n)     o[base] = ov.x;
        if (base + 1 < n) o[base + 1] = ov.y;
        if (base + 2 < n) o[base + 2] = ov.z;
        if (base + 3 < n) o[base + 3] = ov.w;
    }
    if (tid == 255) p[blockIdx.x] = sh[255];
}

__global__ void scan_part_kernel(int* __restrict__ p, int* __restrict__ tot, int nb) {
    __shared__ int sh[256];
    int tid = threadIdx.x;
    int v = (tid < nb) ? p[tid] : 0;
    sh[tid] = v;
    __syncthreads();
    for (int off = 1; off < 256; off <<= 1) {
        int t = (tid >= off) ? sh[tid - off] : 0;
        __syncthreads();
        sh[tid] += t;
        __syncthreads();
    }
    if (tid < nb) p[tid] = sh[tid] - v;
    if (tid == 255) *tot = sh[255];
}

__global__ void scan_add_kernel(int* __restrict__ o, const int* __restrict__ p, int n) {
    int off = p[blockIdx.x];
    int base = blockIdx.x * 1024 + threadIdx.x * 4;
    if (base + 3 < n) {
        int4 v = *(const int4*)(o + base);
        v.x += off; v.y += off; v.z += off; v.w += off;
        *(int4*)(o + base) = v;
    } else {
        if (base < n)     o[base] += off;
        if (base + 1 < n) o[base + 1] += off;
        if (base + 2 < n) o[base + 2] += off;
        if (base + 3 < n) o[base + 3] += off;
    }
}

// ---------------- per-copy cursor bases + self-loop + sentinel pads ----------------
__global__ void base_fill_kernel(int* __restrict__ deg8 /* in: counts, out: cursors */,
                                 const int* __restrict__ rowptr, int* __restrict__ csr, int N) {
    int d = blockIdx.x * 256 + threadIdx.x;
    if (d >= N) return;
    int base = rowptr[d];
    csr[base] = d;  // self loop at slot 0
    int run = base + 1;
    int cnt[8];
#pragma unroll
    for (int c = 0; c < 8; ++c) cnt[c] = deg8[(size_t)c * N + d];
#pragma unroll
    for (int c = 0; c < 8; ++c) { deg8[(size_t)c * N + d] = run; run += cnt[c]; }
    int rend = rowptr[d + 1];
    for (int p = run; p < rend; ++p) csr[p] = N;  // sentinel pads
    if (d == 0) {
        int tot = rowptr[N];
        for (int k = 0; k < 64; ++k) csr[tot + k] = N;  // prefetch margin
    }
}

// ---------------- 8-way scatter (4 edges/thread), copy mapping == hist8 ----------------
__global__ void scatter8_kernel(const int* __restrict__ ei, int* __restrict__ base8,
                                int* __restrict__ csr, int E, int N) {
    int t = blockIdx.x * 256 + threadIdx.x;
    int* cur = base8 + (size_t)(blockIdx.x & 7) * N;
    int e0 = t * 4;
    if (e0 + 3 < E) {
        int4 s4 = *(const int4*)(ei + e0);
        int4 d4 = *(const int4*)(ei + E + e0);
        int p;
        p = atomicAdd(&cur[d4.x], 1); csr[p] = s4.x;
        p = atomicAdd(&cur[d4.y], 1); csr[p] = s4.y;
        p = atomicAdd(&cur[d4.z], 1); csr[p] = s4.z;
        p = atomicAdd(&cur[d4.w], 1); csr[p] = s4.w;
    } else if (e0 < E) {
        for (int j = e0; j < E; ++j) {
            int p = atomicAdd(&cur[ei[E + j]], 1);
            csr[p] = ei[j];
        }
    }
}

// ---------------- fused GEMM + attention coefficients ----------------
// 64x128 tile, 256 threads, each thread 8 rows x 4 cols.
// Block 0 additionally writes the sentinel row (h[n]=0, asrc[n]=-inf).
template <int K>
__global__ void gemm_att_kernel(const float* __restrict__ x, const float* __restrict__ W,
                                const float* __restrict__ as_, const float* __restrict__ ad_,
                                float* __restrict__ h, float* __restrict__ asrc,
                                float* __restrict__ adst, int n) {
    const int ROWS = 64;
    __shared__ float xs[ROWS][HC];
    int tx = threadIdx.x & 31;
    int ty = threadIdx.x >> 5;
    int row0 = blockIdx.x * ROWS;

    if (blockIdx.x == 0) {
        if (threadIdx.x < HC) h[(size_t)n * HC + threadIdx.x] = 0.f;
        if (threadIdx.x < H)  asrc[(size_t)n * H + threadIdx.x] = -INFINITY;
    }

    const int NV = ROWS * K / 4;
    for (int idx = threadIdx.x; idx < NV; idx += 256) {
        int rr = idx / (K / 4), kk = idx % (K / 4);
        int gr = row0 + rr;
        float4 v = (gr < n) ? ((const float4*)(x + (size_t)gr * K))[kk]
                            : make_float4(0.f, 0.f, 0.f, 0.f);
        *(float4*)(&xs[rr][kk * 4]) = v;
    }
    __syncthreads();

    const float* Wc = W + tx * 4;
    float acc[8][4];
#pragma unroll
    for (int r = 0; r < 8; ++r)
#pragma unroll
        for (int c = 0; c < 4; ++c) acc[r][c] = 0.f;

    for (int k = 0; k < K; k += 4) {
        float4 wv[4];
#pragma unroll
        for (int kk = 0; kk < 4; ++kk)
            wv[kk] = *(const float4*)(Wc + (size_t)(k + kk) * HC);
#pragma unroll
        for (int r = 0; r < 8; ++r) {
            float4 xr = *(const float4*)(&xs[ty * 8 + r][k]);
            acc[r][0] = fmaf(xr.x, wv[0].x, acc[r][0]);
            acc[r][1] = fmaf(xr.x, wv[0].y, acc[r][1]);
            acc[r][2] = fmaf(xr.x, wv[0].z, acc[r][2]);
            acc[r][3] = fmaf(xr.x, wv[0].w, acc[r][3]);
            acc[r][0] = fmaf(xr.y, wv[1].x, acc[r][0]);
            acc[r][1] = fmaf(xr.y, wv[1].y, acc[r][1]);
            acc[r][2] = fmaf(xr.y, wv[1].z, acc[r][2]);
            acc[r][3] = fmaf(xr.y, wv[1].w, acc[r][3]);
            acc[r][0] = fmaf(xr.z, wv[2].x, acc[r][0]);
            acc[r][1] = fmaf(xr.z, wv[2].y, acc[r][1]);
            acc[r][2] = fmaf(xr.z, wv[2].z, acc[r][2]);
            acc[r][3] = fmaf(xr.z, wv[2].w, acc[r][3]);
            acc[r][0] = fmaf(xr.w, wv[3].x, acc[r][0]);
            acc[r][1] = fmaf(xr.w, wv[3].y, acc[r][1]);
            acc[r][2] = fmaf(xr.w, wv[3].z, acc[r][2]);
            acc[r][3] = fmaf(xr.w, wv[3].w, acc[r][3]);
        }
    }
    __syncthreads();
#pragma unroll
    for (int r = 0; r < 8; ++r) {
        float4 o = make_float4(acc[r][0], acc[r][1], acc[r][2], acc[r][3]);
        *(float4*)(&xs[ty * 8 + r][tx * 4]) = o;
        int row = row0 + ty * 8 + r;
        if (row < n) *(float4*)(h + (size_t)row * HC + tx * 4) = o;
    }
    __syncthreads();

#pragma unroll
    for (int rep = 0; rep < 2; ++rep) {
        int pidx = threadIdx.x + rep * 256;
        int row = pidx >> 3;
        int hd = pidx & 7;
        if (row0 + row < n) {
            const float4* hv = (const float4*)&xs[row][hd * 16];
            const float4* sv = (const float4*)(as_ + hd * 16);
            const float4* dv = (const float4*)(ad_ + hd * 16);
            float s = 0.f, d = 0.f;
#pragma unroll
            for (int j = 0; j < 4; ++j) {
                float4 a = hv[j], u = sv[j], v = dv[j];
                s += a.x * u.x + a.y * u.y + a.z * u.z + a.w * u.w;
                d += a.x * v.x + a.y * v.y + a.z * v.z + a.w * v.w;
            }
            asrc[(size_t)(row0 + row) * H + hd] = s;
            adst[(size_t)(row0 + row) * H + hd] = d;
        }
    }
}

// ---------------- fused GAT aggregation: one wave per destination ----------------
// No-max softmax (scores bounded; shift-invariance => identical alpha).
// Sentinel-padded rows, straight-line body, 3-stage 8-deep pipeline.
__global__ void gat_agg_kernel(const int* __restrict__ rowptr, const int* __restrict__ csr_src,
                               const float* __restrict__ h, const float* __restrict__ asrc,
                               const float* __restrict__ adst, const float* __restrict__ bias,
                               float* __restrict__ out, int N) {
    int dst = (blockIdx.x * 256 + threadIdx.x) >> 6;  // one wave per dst
    if (dst >= N) return;
    int lane = threadIdx.x & 63;
    int hd = lane >> 3;
    int beg = rowptr[dst], end = rowptr[dst + 1];
    float ad = adst[(size_t)dst * H + hd];
    const float2* h2 = (const float2*)h;  // row stride = 64 float2

    float z = 0.f, a0 = 0.f, a1 = 0.f;
    int i0, i1, i2, i3, i4, i5, i6, i7;
    float e0, e1, e2, e3, e4, e5, e6, e7;
    float2 v0, v1, v2, v3, v4, v5, v6, v7;

#define LOADI(S, J) i##S = csr_src[(J)];
#define LOADV(S)                                                           \
    { e##S = asrc[(size_t)i##S * H + hd]; v##S = h2[(size_t)i##S * 64 + lane]; }
#define PROCE(S)                                                           \
    {   float e = e##S + ad;                                               \
        e = e > 0.f ? e : NEG_SLOPE * e;                                   \
        float w = __expf(e);                                               \
        z += w;                                                            \
        a0 = fmaf(w, v##S.x, a0);                                          \
        a1 = fmaf(w, v##S.y, a1);                                          \
    }
    LOADI(0, beg)     LOADI(1, beg + 1) LOADI(2, beg + 2) LOADI(3, beg + 3)
    LOADI(4, beg + 4) LOADI(5, beg + 5) LOADI(6, beg + 6) LOADI(7, beg + 7)
    LOADV(0) LOADV(1) LOADV(2) LOADV(3) LOADV(4) LOADV(5) LOADV(6) LOADV(7)
    LOADI(0, beg + 8)  LOADI(1, beg + 9)  LOADI(2, beg + 10) LOADI(3, beg + 11)
    LOADI(4, beg + 12) LOADI(5, beg + 13) LOADI(6, beg + 14) LOADI(7, beg + 15)

    for (int j = beg; j < end; j += 8) {
        PROCE(0) LOADV(0)
        PROCE(1) LOADV(1)
        PROCE(2) LOADV(2)
        PROCE(3) LOADV(3)
        PROCE(4) LOADV(4)
        PROCE(5) LOADV(5)
        PROCE(6) LOADV(6)
        PROCE(7) LOADV(7)
        LOADI(0, j + 16) LOADI(1, j + 17) LOADI(2, j + 18) LOADI(3, j + 19)
        LOADI(4, j + 20) LOADI(5, j + 21) LOADI(6, j + 22) LOADI(7, j + 23)
    }
#undef LOADI
#undef LOADV
#undef PROCE
    float inv = 1.f / (z + 1e-16f);
    int c2 = lane * 2;
    float r0 = fmaxf(a0 * inv + bias[c2], 0.f);
    float r1 = fmaxf(a1 * inv + bias[c2 + 1], 0.f);
    *(float2*)(out + (size_t)dst * HC + c2) = make_float2(r0, r1);
}

// ---------------- fused global mean pool + MLP: one block (128 threads) per graph ---
__global__ void pool_mlp_kernel(const float* __restrict__ x, const int* __restrict__ gptr,
                                const float* __restrict__ fc1w, const float* __restrict__ fc1b,
                                const float* __restrict__ fc2w, const float* __restrict__ fc2b,
                                float* __restrict__ out, int G) {
    __shared__ float sp[HC];
    __shared__ float sh[10];
    int g = blockIdx.x;
    int c = threadIdx.x;  // 0..127
    int beg = gptr[g], end = gptr[g + 1];
    float acc = 0.f;
    for (int n = beg; n < end; ++n) acc += x[(size_t)n * HC + c];
    sp[c] = acc / fmaxf((float)(end - beg), 1.f);
    __syncthreads();
    if (c < 10) {
        float s = fc1b[c];
        for (int k = 0; k < HC; ++k) s = fmaf(sp[k], fc1w[k * 10 + c], s);
        sh[c] = fmaxf(s, 0.f);
    }
    __syncthreads();
    if (c == 0) {
        float o = fc2b[0];
#pragma unroll
        for (int j = 0; j < 10; ++j) o = fmaf(sh[j], fc2w[j], o);
        out[g] = o;
    }
}

extern "C" void kernel_launch(void* const* d_in, const int* in_sizes, int n_in,
                              void* d_out, int out_size, void* d_ws, size_t ws_size,
                              hipStream_t stream) {
    const int N = in_sizes[0] / 64;   // 50000
    const int E = in_sizes[1] / 2;    // 600000
    const int G = out_size;           // 500
    const int CSR_CAP = E + 8 * N + 64;  // padded-row worst case + prefetch margin

    const float* x     = (const float*)d_in[0];
    const int*   ei    = (const int*)d_in[1];
    const int*   batch = (const int*)d_in[2];
    const float* W1 = (const float*)d_in[3];
    const float* as1 = (const float*)d_in[4];
    const float* ad1 = (const float*)d_in[5];
    const float* b1 = (const float*)d_in[6];
    const float* W2 = (const float*)d_in[7];
    const float* as2 = (const float*)d_in[8];
    const float* ad2 = (const float*)d_in[9];
    const float* b2 = (const float*)d_in[10];
    const float* W3 = (const float*)d_in[11];
    const float* as3 = (const float*)d_in[12];
    const float* ad3 = (const float*)d_in[13];
    const float* b3 = (const float*)d_in[14];
    const float* fc1w = (const float*)d_in[15];
    const float* fc1b = (const float*)d_in[16];
    const float* fc2w = (const float*)d_in[17];
    const float* fc2b = (const float*)d_in[18];

    // -------- workspace layout --------
    float* ws = (float*)d_ws;
    float* h    = ws;                            // (N+1)*128
    float* xb0  = h + (size_t)(N + 1) * HC;      // N*128
    float* xb1  = xb0 + (size_t)N * HC;          // N*128
    float* asrc = xb1 + (size_t)N * HC;          // (N+1)*8
    float* adst = asrc + (size_t)(N + 1) * H;    // N*8
    int* ints   = (int*)(adst + (size_t)N * H);
    int* deg8   = ints;                          // 8*N  (becomes base8 cursors)
    int* deg    = deg8 + (size_t)8 * N;          // N
    int* rowptr = deg + N;                       // N+16
    int* gptr   = rowptr + N + 16;               // G+16
    int* partN  = gptr + G + 16;                 // 256
    int* csr    = partN + 256;                   // CSR_CAP

    dim3 blk(256);
    int grid4   = ((E + 3) / 4 + 255) / 256;     // covers E/4 and N/4 threads
    int grid_n  = (N + 255) / 256;
    int grid_agg = (N * 64 + 255) / 256;
    int nbN = (N + 1023) / 1024;

    // -------- one-time CSR build (graph shared by all 3 layers) --------
    init_kernel<<<(8 * N + 255) / 256, blk, 0, stream>>>(deg8, 8 * N);
    hist8_gptr_kernel<<<grid4, blk, 0, stream>>>(ei, batch, deg8, gptr, E, N, G);
    deg_reduce_kernel<<<grid_n, blk, 0, stream>>>(deg8, deg, N);
    scan_blk_kernel<<<nbN, blk, 0, stream>>>(deg, rowptr, partN, N);
    scan_part_kernel<<<1, blk, 0, stream>>>(partN, rowptr + N, nbN);
    scan_add_kernel<<<nbN, blk, 0, stream>>>(rowptr, partN, N);
    base_fill_kernel<<<grid_n, blk, 0, stream>>>(deg8, rowptr, csr, N);
    scatter8_kernel<<<grid4, blk, 0, stream>>>(ei, deg8, csr, E, N);

    auto run_layer = [&](const float* xin, int K, const float* W, const float* as_,
                         const float* ad_, const float* b, float* out) {
        if (K == 64)
            gemm_att_kernel<64><<<(N + 63) / 64, blk, 0, stream>>>(xin, W, as_, ad_,
                                                                   h, asrc, adst, N);
        else
            gemm_att_kernel<128><<<(N + 63) / 64, blk, 0, stream>>>(xin, W, as_, ad_,
                                                                    h, asrc, adst, N);
        gat_agg_kernel<<<grid_agg, blk, 0, stream>>>(rowptr, csr, h, asrc, adst, b, out, N);
    };

    run_layer(x,   64,  W1, as1, ad1, b1, xb0);
    run_layer(xb0, 128, W2, as2, ad2, b2, xb1);
    run_layer(xb1, 128, W3, as3, ad3, b3, xb0);

    pool_mlp_kernel<<<G, dim3(128), 0, stream>>>(xb0, gptr, fc1w, fc1b, fc2w, fc2b,
                                                 (float*)d_out, G);
}